// Round 1
// baseline (1437.982 us; speedup 1.0000x reference)
//
#include <hip/hip_runtime.h>
#include <math.h>

#define N_NODES 2048
#define D_MODEL 256
#define D_FEAT 128
#define NHEAD 8
#define DH 32
#define NLAYER 2
#define NEDGE 65536
#define D_FF 1024
#define D_OUT 128
#define MAXDEG 512

// ---------------- degree count ----------------
__global__ void degree_kernel(const int* __restrict__ edge_index,
                              int* __restrict__ deg_out, int* __restrict__ deg_in) {
    int e = blockIdx.x * 256 + threadIdx.x;
    if (e < NEDGE) {
        atomicAdd(&deg_out[edge_index[e]], 1);          // src row
        atomicAdd(&deg_in[edge_index[NEDGE + e]], 1);   // dst row
    }
}

// ---------------- centrality add: h += din_emb[deg_in] + dout_emb[deg_out] ----------------
__global__ void centrality_kernel(float* __restrict__ h,
                                  const float* __restrict__ din_l,
                                  const float* __restrict__ dout_l,
                                  const int* __restrict__ deg_in,
                                  const int* __restrict__ deg_out) {
    int idx = blockIdx.x * 256 + threadIdx.x;   // N*D threads
    int row = idx >> 8;                          // D_MODEL == 256
    int c = idx & 255;
    int di = min(deg_in[row], MAXDEG);
    int dو = min(deg_out[row], MAXDEG);
    h[idx] += din_l[di * D_MODEL + c] + dout_l[dو * D_MODEL + c];
}

// ---------------- layernorm (D=256, one block per row) ----------------
__global__ void layernorm_kernel(const float* __restrict__ x,
                                 const float* __restrict__ g,
                                 const float* __restrict__ b,
                                 float* __restrict__ y) {
    int row = blockIdx.x;
    int tid = threadIdx.x;
    float v = x[row * D_MODEL + tid];
    __shared__ float red[256];
    red[tid] = v; __syncthreads();
    for (int s = 128; s > 0; s >>= 1) { if (tid < s) red[tid] += red[tid + s]; __syncthreads(); }
    float mu = red[0] * (1.0f / D_MODEL);
    __syncthreads();
    float d = v - mu;
    red[tid] = d * d; __syncthreads();
    for (int s = 128; s > 0; s >>= 1) { if (tid < s) red[tid] += red[tid + s]; __syncthreads(); }
    float var = red[0] * (1.0f / D_MODEL);
    float rstd = rsqrtf(var + 1e-5f);
    y[row * D_MODEL + tid] = d * rstd * g[tid] + b[tid];
}

// ---------------- generic tiled fp32 GEMM: C = [C +] A@B + bias, optional exact GELU ----------------
// A[M,K], B[K,Nc], C[M,Nc]; all dims multiples of 32. Block 256, tile 32x32, 4 outputs/thread.
template <int ACT, bool RESID>
__global__ void gemm_kernel(const float* __restrict__ A, const float* __restrict__ B,
                            const float* __restrict__ bias, float* __restrict__ C,
                            int M, int Nc, int K) {
    __shared__ float As[32][33];
    __shared__ float Bs[32][33];
    int tid = threadIdx.x;
    int row0 = blockIdx.y * 32;
    int col0 = blockIdx.x * 32;
    int tr = tid >> 5;      // 0..7
    int tc = tid & 31;      // 0..31
    float acc[4] = {0.f, 0.f, 0.f, 0.f};
    for (int k0 = 0; k0 < K; k0 += 32) {
        #pragma unroll
        for (int i = 0; i < 4; i++) {
            int r = tr + i * 8;
            As[r][tc] = A[(size_t)(row0 + r) * K + k0 + tc];
            Bs[r][tc] = B[(size_t)(k0 + r) * Nc + col0 + tc];
        }
        __syncthreads();
        #pragma unroll
        for (int kk = 0; kk < 32; kk++) {
            float bvv = Bs[kk][tc];
            #pragma unroll
            for (int i = 0; i < 4; i++) acc[i] += As[tr * 4 + i][kk] * bvv;
        }
        __syncthreads();
    }
    float bv = bias[col0 + tc];
    #pragma unroll
    for (int i = 0; i < 4; i++) {
        size_t idx = (size_t)(row0 + tr * 4 + i) * Nc + col0 + tc;
        float val = acc[i] + bv;
        if (ACT == 1) val = val * 0.5f * (1.0f + erff(val * 0.7071067811865476f));
        if (RESID) val += C[idx];
        C[idx] = val;
    }
}

// ---------------- scores = (q @ k^T) * scale + spd_bias ----------------
// grid: (N/32, N/32, H); q,k stored [N, D] with head h at cols h*32..h*32+31
__global__ void scores_kernel(const float* __restrict__ q, const float* __restrict__ k,
                              const float* __restrict__ pos, const float* __restrict__ spd_l,
                              float* __restrict__ scores) {
    int hh = blockIdx.z;
    int i0 = blockIdx.y * 32, j0 = blockIdx.x * 32;
    __shared__ float qs[32][33], ks[32][33];
    __shared__ float spd[11 * NHEAD];
    int tid = threadIdx.x;
    if (tid < 11 * NHEAD) spd[tid] = spd_l[tid];
    int tr = tid >> 5, tc = tid & 31;
    #pragma unroll
    for (int i = 0; i < 4; i++) {
        int r = tr + i * 8;
        qs[r][tc] = q[(size_t)(i0 + r) * D_MODEL + hh * DH + tc];
        ks[r][tc] = k[(size_t)(j0 + r) * D_MODEL + hh * DH + tc];
    }
    __syncthreads();
    float acc[4] = {0.f, 0.f, 0.f, 0.f};
    #pragma unroll
    for (int d = 0; d < 32; d++) {
        float kv = ks[tc][d];
        #pragma unroll
        for (int i = 0; i < 4; i++) acc[i] += qs[tr * 4 + i][d] * kv;
    }
    const float scale = 0.17677669529663687f;  // 1/sqrt(32)
    #pragma unroll
    for (int i = 0; i < 4; i++) {
        int r = i0 + tr * 4 + i;
        int c = j0 + tc;
        float p = pos[(size_t)r * N_NODES + c];
        float bf = p * 10.f + 0.5f;
        bf = fminf(fmaxf(bf, 0.f), 10.f);
        int bucket = (int)bf;
        scores[((size_t)hh * N_NODES + r) * N_NODES + c] = acc[i] * scale + spd[bucket * NHEAD + hh];
    }
}

// ---------------- edge bias scatter-add ----------------
__global__ void edge_bias_kernel(const int* __restrict__ edge_index,
                                 const int* __restrict__ edge_types,
                                 const float* __restrict__ et_l,
                                 float* __restrict__ scores) {
    int idx = blockIdx.x * 256 + threadIdx.x;   // E * H threads
    int e = idx >> 3;
    int hh = idx & 7;
    if (e < NEDGE) {
        int s = edge_index[e];
        int d2 = edge_index[NEDGE + e];
        float val = et_l[edge_types[e] * NHEAD + hh];
        atomicAdd(&scores[((size_t)hh * N_NODES + s) * N_NODES + d2], val);
    }
}

// ---------------- row softmax in-place, one block per (h,row) ----------------
__global__ void softmax_kernel(float* __restrict__ scores) {
    float* p = scores + (size_t)blockIdx.x * N_NODES;
    int tid = threadIdx.x;
    float vals[8];
    float m = -INFINITY;
    #pragma unroll
    for (int i = 0; i < 8; i++) { vals[i] = p[tid + i * 256]; m = fmaxf(m, vals[i]); }
    __shared__ float red[256];
    red[tid] = m; __syncthreads();
    for (int s = 128; s > 0; s >>= 1) { if (tid < s) red[tid] = fmaxf(red[tid], red[tid + s]); __syncthreads(); }
    m = red[0]; __syncthreads();
    float sum = 0.f;
    #pragma unroll
    for (int i = 0; i < 8; i++) { vals[i] = expf(vals[i] - m); sum += vals[i]; }
    red[tid] = sum; __syncthreads();
    for (int s = 128; s > 0; s >>= 1) { if (tid < s) red[tid] += red[tid + s]; __syncthreads(); }
    float inv = 1.0f / red[0];
    #pragma unroll
    for (int i = 0; i < 8; i++) p[tid + i * 256] = vals[i] * inv;
}

// ---------------- attn @ v, per head; grid (N/32, H) ----------------
__global__ void attnv_kernel(const float* __restrict__ attn, const float* __restrict__ v,
                             float* __restrict__ out) {
    int hh = blockIdx.y;
    int i0 = blockIdx.x * 32;
    __shared__ float as_[32][33], vs[32][33];
    int tid = threadIdx.x, tr = tid >> 5, tc = tid & 31;
    float acc[4] = {0.f, 0.f, 0.f, 0.f};
    const float* ap = attn + (size_t)hh * N_NODES * N_NODES;
    for (int j0 = 0; j0 < N_NODES; j0 += 32) {
        #pragma unroll
        for (int i = 0; i < 4; i++) {
            int r = tr + i * 8;
            as_[r][tc] = ap[(size_t)(i0 + r) * N_NODES + j0 + tc];
            vs[r][tc] = v[(size_t)(j0 + r) * D_MODEL + hh * DH + tc];
        }
        __syncthreads();
        #pragma unroll
        for (int j = 0; j < 32; j++) {
            float vv = vs[j][tc];
            #pragma unroll
            for (int i = 0; i < 4; i++) acc[i] += as_[tr * 4 + i][j] * vv;
        }
        __syncthreads();
    }
    #pragma unroll
    for (int i = 0; i < 4; i++)
        out[(size_t)(i0 + tr * 4 + i) * D_MODEL + hh * DH + tc] = acc[i];
}

extern "C" void kernel_launch(void* const* d_in, const int* in_sizes, int n_in,
                              void* d_out, int out_size, void* d_ws, size_t ws_size,
                              hipStream_t stream) {
    const float* x          = (const float*)d_in[0];
    const int*   edge_index = (const int*)d_in[1];
    const int*   edge_types = (const int*)d_in[2];
    const float* pos        = (const float*)d_in[3];
    const float* W_emb      = (const float*)d_in[4];
    const float* b_emb      = (const float*)d_in[5];
    const float* Wq         = (const float*)d_in[6];
    const float* Wk         = (const float*)d_in[7];
    const float* Wv         = (const float*)d_in[8];
    const float* Wo         = (const float*)d_in[9];
    const float* bq         = (const float*)d_in[10];
    const float* bk         = (const float*)d_in[11];
    const float* bv         = (const float*)d_in[12];
    const float* bo         = (const float*)d_in[13];
    const float* spd_table  = (const float*)d_in[14];
    const float* edge_table = (const float*)d_in[15];
    const float* din_emb    = (const float*)d_in[16];
    const float* dout_emb   = (const float*)d_in[17];
    const float* ln1_g      = (const float*)d_in[18];
    const float* ln1_b      = (const float*)d_in[19];
    const float* ln2_g      = (const float*)d_in[20];
    const float* ln2_b      = (const float*)d_in[21];
    const float* W1         = (const float*)d_in[22];
    const float* b1         = (const float*)d_in[23];
    const float* W2         = (const float*)d_in[24];
    const float* b2         = (const float*)d_in[25];
    const float* W_out      = (const float*)d_in[26];
    const float* b_out      = (const float*)d_in[27];
    float* out = (float*)d_out;

    // workspace layout
    char* base = (char*)d_ws;
    int* deg_out = (int*)base;            base += (size_t)N_NODES * 4;
    int* deg_in  = (int*)base;            base += (size_t)N_NODES * 4;
    float* h     = (float*)base;          base += (size_t)N_NODES * D_MODEL * 4;
    float* xn    = (float*)base;          base += (size_t)N_NODES * D_MODEL * 4;
    float* q     = (float*)base;          base += (size_t)N_NODES * D_MODEL * 4;
    float* k     = (float*)base;          base += (size_t)N_NODES * D_MODEL * 4;
    float* v     = (float*)base;          base += (size_t)N_NODES * D_MODEL * 4;
    float* aout  = (float*)base;          base += (size_t)N_NODES * D_MODEL * 4;
    float* ffn   = (float*)base;          base += (size_t)N_NODES * D_FF * 4;
    float* scores = (float*)base;         base += (size_t)NHEAD * N_NODES * N_NODES * 4;

    // degrees
    hipMemsetAsync(deg_out, 0, (size_t)N_NODES * 4 * 2, stream);
    degree_kernel<<<NEDGE / 256, 256, 0, stream>>>(edge_index, deg_out, deg_in);

    // embed: h = x @ W_emb + b_emb   [2048,128]x[128,256]
    gemm_kernel<0, false><<<dim3(D_MODEL / 32, N_NODES / 32), 256, 0, stream>>>(
        x, W_emb, b_emb, h, N_NODES, D_MODEL, D_FEAT);

    for (int l = 0; l < NLAYER; l++) {
        const float* Wq_l = Wq + (size_t)l * D_MODEL * D_MODEL;
        const float* Wk_l = Wk + (size_t)l * D_MODEL * D_MODEL;
        const float* Wv_l = Wv + (size_t)l * D_MODEL * D_MODEL;
        const float* Wo_l = Wo + (size_t)l * D_MODEL * D_MODEL;
        const float* W1_l = W1 + (size_t)l * D_MODEL * D_FF;
        const float* W2_l = W2 + (size_t)l * D_FF * D_MODEL;

        centrality_kernel<<<N_NODES * D_MODEL / 256, 256, 0, stream>>>(
            h, din_emb + (size_t)l * (MAXDEG + 1) * D_MODEL,
            dout_emb + (size_t)l * (MAXDEG + 1) * D_MODEL, deg_in, deg_out);

        layernorm_kernel<<<N_NODES, 256, 0, stream>>>(h, ln1_g + l * D_MODEL, ln1_b + l * D_MODEL, xn);

        dim3 gproj(D_MODEL / 32, N_NODES / 32);
        gemm_kernel<0, false><<<gproj, 256, 0, stream>>>(xn, Wq_l, bq + l * D_MODEL, q, N_NODES, D_MODEL, D_MODEL);
        gemm_kernel<0, false><<<gproj, 256, 0, stream>>>(xn, Wk_l, bk + l * D_MODEL, k, N_NODES, D_MODEL, D_MODEL);
        gemm_kernel<0, false><<<gproj, 256, 0, stream>>>(xn, Wv_l, bv + l * D_MODEL, v, N_NODES, D_MODEL, D_MODEL);

        scores_kernel<<<dim3(N_NODES / 32, N_NODES / 32, NHEAD), 256, 0, stream>>>(
            q, k, pos, spd_table + (size_t)l * 11 * NHEAD, scores);

        edge_bias_kernel<<<NEDGE * NHEAD / 256, 256, 0, stream>>>(
            edge_index, edge_types, edge_table + (size_t)l * 8 * NHEAD, scores);

        softmax_kernel<<<NHEAD * N_NODES, 256, 0, stream>>>(scores);

        attnv_kernel<<<dim3(N_NODES / 32, NHEAD), 256, 0, stream>>>(scores, v, aout);

        gemm_kernel<0, true><<<gproj, 256, 0, stream>>>(aout, Wo_l, bo + l * D_MODEL, h, N_NODES, D_MODEL, D_MODEL);

        layernorm_kernel<<<N_NODES, 256, 0, stream>>>(h, ln2_g + l * D_MODEL, ln2_b + l * D_MODEL, xn);

        gemm_kernel<1, false><<<dim3(D_FF / 32, N_NODES / 32), 256, 0, stream>>>(
            xn, W1_l, b1 + l * D_FF, ffn, N_NODES, D_FF, D_MODEL);

        gemm_kernel<0, true><<<gproj, 256, 0, stream>>>(ffn, W2_l, b2 + l * D_MODEL, h, N_NODES, D_MODEL, D_FF);
    }

    gemm_kernel<0, false><<<dim3(D_OUT / 32, N_NODES / 32), 256, 0, stream>>>(
        h, W_out, b_out, out, N_NODES, D_OUT, D_MODEL);
}

// Round 2
// 596.065 us; speedup vs baseline: 2.4125x; 2.4125x over previous
//
#include <hip/hip_runtime.h>
#include <math.h>

#define N_NODES 2048
#define D_MODEL 256
#define D_FEAT 128
#define NHEAD 8
#define DH 32
#define NLAYER 2
#define NEDGE 65536
#define D_FF 1024
#define D_OUT 128
#define MAXDEG 512
#define KS 8           // split-K factor for attnv
#define KCHUNK 256     // K per attnv block

typedef __attribute__((ext_vector_type(8))) short short8;
typedef __attribute__((ext_vector_type(4))) float f32x4;
typedef __attribute__((ext_vector_type(4))) unsigned short u16x4;

__device__ __forceinline__ unsigned short f2bf(float f) {
    unsigned u = __float_as_uint(f);
    unsigned r = (u + 0x7FFFu + ((u >> 16) & 1u)) >> 16;
    return (unsigned short)r;
}

// ---------------- degree count ----------------
__global__ void degree_kernel(const int* __restrict__ edge_index,
                              int* __restrict__ deg_out, int* __restrict__ deg_in) {
    int e = blockIdx.x * 256 + threadIdx.x;
    if (e < NEDGE) {
        atomicAdd(&deg_out[edge_index[e]], 1);
        atomicAdd(&deg_in[edge_index[NEDGE + e]], 1);
    }
}

// ---------------- centrality add ----------------
__global__ void centrality_kernel(float* __restrict__ h,
                                  const float* __restrict__ din_l,
                                  const float* __restrict__ dout_l,
                                  const int* __restrict__ deg_in,
                                  const int* __restrict__ deg_out) {
    int idx = blockIdx.x * 256 + threadIdx.x;
    int row = idx >> 8;
    int c = idx & 255;
    int di = min(deg_in[row], MAXDEG);
    int dn = min(deg_out[row], MAXDEG);
    h[idx] += din_l[di * D_MODEL + c] + dout_l[dn * D_MODEL + c];
}

// ---------------- layernorm ----------------
__global__ void layernorm_kernel(const float* __restrict__ x,
                                 const float* __restrict__ g,
                                 const float* __restrict__ b,
                                 float* __restrict__ y) {
    int row = blockIdx.x;
    int tid = threadIdx.x;
    float v = x[row * D_MODEL + tid];
    __shared__ float red[256];
    red[tid] = v; __syncthreads();
    for (int s = 128; s > 0; s >>= 1) { if (tid < s) red[tid] += red[tid + s]; __syncthreads(); }
    float mu = red[0] * (1.0f / D_MODEL);
    __syncthreads();
    float d = v - mu;
    red[tid] = d * d; __syncthreads();
    for (int s = 128; s > 0; s >>= 1) { if (tid < s) red[tid] += red[tid + s]; __syncthreads(); }
    float rstd = rsqrtf(red[0] * (1.0f / D_MODEL) + 1e-5f);
    y[row * D_MODEL + tid] = d * rstd * g[tid] + b[tid];
}

// ---------------- fp32 GEMM: 32(M)x64(N) tile, 8 outputs/thread ----------------
template <int ACT, bool RESID>
__global__ void gemm_kernel(const float* __restrict__ A, const float* __restrict__ B,
                            const float* __restrict__ bias, float* __restrict__ C,
                            int M, int Nc, int K) {
    __shared__ __align__(16) float At[32][34];   // [k][m]
    __shared__ __align__(16) float Bs[32][68];   // [k][n]
    int tid = threadIdx.x;
    int m0 = blockIdx.y * 32, c0 = blockIdx.x * 64;
    int tc = tid & 15, tr = tid >> 4;
    float acc[2][4] = {};
    for (int k0 = 0; k0 < K; k0 += 32) {
        int m = tid >> 3, kg = tid & 7;
        float4 av = *(const float4*)&A[(size_t)(m0 + m) * K + k0 + kg * 4];
        At[kg * 4 + 0][m] = av.x; At[kg * 4 + 1][m] = av.y;
        At[kg * 4 + 2][m] = av.z; At[kg * 4 + 3][m] = av.w;
        #pragma unroll
        for (int i = 0; i < 2; i++) {
            int kk = (tid >> 4) + i * 16;
            *(float4*)&Bs[kk][(tid & 15) * 4] =
                *(const float4*)&B[(size_t)(k0 + kk) * Nc + c0 + (tid & 15) * 4];
        }
        __syncthreads();
        #pragma unroll
        for (int kk = 0; kk < 32; kk++) {
            float2 a2 = *(const float2*)&At[kk][tr * 2];
            float4 b4 = *(const float4*)&Bs[kk][tc * 4];
            acc[0][0] += a2.x * b4.x; acc[0][1] += a2.x * b4.y;
            acc[0][2] += a2.x * b4.z; acc[0][3] += a2.x * b4.w;
            acc[1][0] += a2.y * b4.x; acc[1][1] += a2.y * b4.y;
            acc[1][2] += a2.y * b4.z; acc[1][3] += a2.y * b4.w;
        }
        __syncthreads();
    }
    #pragma unroll
    for (int i = 0; i < 2; i++) {
        int row = m0 + tr * 2 + i;
        size_t base = (size_t)row * Nc + c0 + tc * 4;
        float4 res;
        float* rp = (float*)&res;
        #pragma unroll
        for (int j = 0; j < 4; j++) {
            float val = acc[i][j] + bias[c0 + tc * 4 + j];
            if (ACT == 1) val = val * 0.5f * (1.0f + erff(val * 0.7071067811865476f));
            if (RESID) val += C[base + j];
            rp[j] = val;
        }
        *(float4*)&C[base] = res;
    }
}

// ---------------- fused QKV GEMM (Nc_total = 768 mapped to 3 weight sets) ----------------
__global__ void qkv_gemm_kernel(const float* __restrict__ A,
                                const float* __restrict__ Wq, const float* __restrict__ Wk,
                                const float* __restrict__ Wv,
                                const float* __restrict__ bq, const float* __restrict__ bk,
                                const float* __restrict__ bv,
                                float* __restrict__ q, float* __restrict__ k, float* __restrict__ v) {
    __shared__ __align__(16) float At[32][34];
    __shared__ __align__(16) float Bs[32][68];
    int tid = threadIdx.x;
    int m0 = blockIdx.y * 32;
    int c0g = blockIdx.x * 64;
    int sel = c0g >> 8;                 // 0,1,2 -> q,k,v
    int c0 = c0g & 255;
    const float* B = (sel == 0) ? Wq : (sel == 1) ? Wk : Wv;
    const float* bias = (sel == 0) ? bq : (sel == 1) ? bk : bv;
    float* C = (sel == 0) ? q : (sel == 1) ? k : v;
    int tc = tid & 15, tr = tid >> 4;
    float acc[2][4] = {};
    for (int k0 = 0; k0 < D_MODEL; k0 += 32) {
        int m = tid >> 3, kg = tid & 7;
        float4 av = *(const float4*)&A[(size_t)(m0 + m) * D_MODEL + k0 + kg * 4];
        At[kg * 4 + 0][m] = av.x; At[kg * 4 + 1][m] = av.y;
        At[kg * 4 + 2][m] = av.z; At[kg * 4 + 3][m] = av.w;
        #pragma unroll
        for (int i = 0; i < 2; i++) {
            int kk = (tid >> 4) + i * 16;
            *(float4*)&Bs[kk][(tid & 15) * 4] =
                *(const float4*)&B[(size_t)(k0 + kk) * D_MODEL + c0 + (tid & 15) * 4];
        }
        __syncthreads();
        #pragma unroll
        for (int kk = 0; kk < 32; kk++) {
            float2 a2 = *(const float2*)&At[kk][tr * 2];
            float4 b4 = *(const float4*)&Bs[kk][tc * 4];
            acc[0][0] += a2.x * b4.x; acc[0][1] += a2.x * b4.y;
            acc[0][2] += a2.x * b4.z; acc[0][3] += a2.x * b4.w;
            acc[1][0] += a2.y * b4.x; acc[1][1] += a2.y * b4.y;
            acc[1][2] += a2.y * b4.z; acc[1][3] += a2.y * b4.w;
        }
        __syncthreads();
    }
    #pragma unroll
    for (int i = 0; i < 2; i++) {
        int row = m0 + tr * 2 + i;
        size_t base = (size_t)row * D_MODEL + c0 + tc * 4;
        float4 res;
        float* rp = (float*)&res;
        #pragma unroll
        for (int j = 0; j < 4; j++) rp[j] = acc[i][j] + bias[c0 + tc * 4 + j];
        *(float4*)&C[base] = res;
    }
}

// ---------------- transpose-cast v -> vbt (bf16 [D][N]) ----------------
__global__ void vbt_cast_kernel(const float* __restrict__ v, unsigned short* __restrict__ vbt) {
    __shared__ float tile[32][33];
    int c0 = blockIdx.x * 32, r0 = blockIdx.y * 32;
    int tid = threadIdx.x;
    int r = tid >> 3, cg = tid & 7;
    float4 v4 = *(const float4*)&v[(size_t)(r0 + r) * D_MODEL + c0 + cg * 4];
    tile[r][cg * 4 + 0] = v4.x; tile[r][cg * 4 + 1] = v4.y;
    tile[r][cg * 4 + 2] = v4.z; tile[r][cg * 4 + 3] = v4.w;
    __syncthreads();
    int c = tid >> 3, rg = tid & 7;
    u16x4 o;
    #pragma unroll
    for (int j = 0; j < 4; j++) o[j] = f2bf(tile[rg * 4 + j][c]);
    *(u16x4*)&vbt[(size_t)(c0 + c) * N_NODES + r0 + rg * 4] = o;
}

// ---------------- scores = (q@k^T)*scale + spd bias, bf16 MFMA ----------------
// grid (N/64, N/64, H), block 256 (4 waves); each wave: 16 rows x 64 cols
__global__ void scores_mfma_kernel(const float* __restrict__ q, const float* __restrict__ k,
                                   const float* __restrict__ pos, const float* __restrict__ spd_l,
                                   float* __restrict__ scores) {
    __shared__ __align__(16) short qs[64][40];
    __shared__ __align__(16) short ks[64][40];
    __shared__ float spd[11 * NHEAD];
    int tid = threadIdx.x;
    int hh = blockIdx.z;
    int i0 = blockIdx.y * 64, j0 = blockIdx.x * 64;
    if (tid < 11 * NHEAD) spd[tid] = spd_l[tid];
    {
        int r = tid >> 2, cg = tid & 3;
        float4 a = *(const float4*)&q[(size_t)(i0 + r) * D_MODEL + hh * DH + cg * 8];
        float4 b = *(const float4*)&q[(size_t)(i0 + r) * D_MODEL + hh * DH + cg * 8 + 4];
        short8 sv;
        sv[0] = f2bf(a.x); sv[1] = f2bf(a.y); sv[2] = f2bf(a.z); sv[3] = f2bf(a.w);
        sv[4] = f2bf(b.x); sv[5] = f2bf(b.y); sv[6] = f2bf(b.z); sv[7] = f2bf(b.w);
        *(short8*)&qs[r][cg * 8] = sv;
        float4 c = *(const float4*)&k[(size_t)(j0 + r) * D_MODEL + hh * DH + cg * 8];
        float4 d = *(const float4*)&k[(size_t)(j0 + r) * D_MODEL + hh * DH + cg * 8 + 4];
        short8 kv;
        kv[0] = f2bf(c.x); kv[1] = f2bf(c.y); kv[2] = f2bf(c.z); kv[3] = f2bf(c.w);
        kv[4] = f2bf(d.x); kv[5] = f2bf(d.y); kv[6] = f2bf(d.z); kv[7] = f2bf(d.w);
        *(short8*)&ks[r][cg * 8] = kv;
    }
    __syncthreads();
    int w = tid >> 6, lane = tid & 63;
    int wrow = w * 16;
    int m = lane & 15, quad = lane >> 4;
    short8 av = *(const short8*)&qs[wrow + m][quad * 8];
    f32x4 acc[4];
    #pragma unroll
    for (int t = 0; t < 4; t++) {
        f32x4 z = {0.f, 0.f, 0.f, 0.f};
        short8 bv = *(const short8*)&ks[t * 16 + m][quad * 8];
        acc[t] = __builtin_amdgcn_mfma_f32_16x16x32_bf16(av, bv, z, 0, 0, 0);
    }
    const float scale = 0.17677669529663687f;
    #pragma unroll
    for (int t = 0; t < 4; t++) {
        #pragma unroll
        for (int reg = 0; reg < 4; reg++) {
            int row = i0 + wrow + quad * 4 + reg;
            int col = j0 + t * 16 + m;
            float p = pos[(size_t)row * N_NODES + col];
            float bf = fminf(fmaxf(p * 10.f + 0.5f, 0.f), 10.f);
            int bucket = (int)bf;
            scores[((size_t)hh * N_NODES + row) * N_NODES + col] =
                acc[t][reg] * scale + spd[bucket * NHEAD + hh];
        }
    }
}

// ---------------- edge bias scatter-add (fp32 atomics) ----------------
__global__ void edge_bias_kernel(const int* __restrict__ edge_index,
                                 const int* __restrict__ edge_types,
                                 const float* __restrict__ et_l,
                                 float* __restrict__ scores) {
    int idx = blockIdx.x * 256 + threadIdx.x;
    int e = idx >> 3;
    int hh = idx & 7;
    if (e < NEDGE) {
        int s = edge_index[e];
        int d2 = edge_index[NEDGE + e];
        float val = et_l[edge_types[e] * NHEAD + hh];
        atomicAdd(&scores[((size_t)hh * N_NODES + s) * N_NODES + d2], val);
    }
}

// ---------------- softmax: fp32 row in, bf16 row out (in place, first half) ----------------
__global__ void softmax_kernel(float* __restrict__ scores) {
    float* p = scores + (size_t)blockIdx.x * N_NODES;
    unsigned short* pb = (unsigned short*)p;
    int tid = threadIdx.x;
    float vals[8];
    float m = -INFINITY;
    #pragma unroll
    for (int i = 0; i < 8; i++) { vals[i] = p[tid + i * 256]; m = fmaxf(m, vals[i]); }
    __shared__ float red[256];
    red[tid] = m; __syncthreads();
    for (int s = 128; s > 0; s >>= 1) { if (tid < s) red[tid] = fmaxf(red[tid], red[tid + s]); __syncthreads(); }
    m = red[0]; __syncthreads();
    float sum = 0.f;
    #pragma unroll
    for (int i = 0; i < 8; i++) { vals[i] = expf(vals[i] - m); sum += vals[i]; }
    red[tid] = sum; __syncthreads();
    for (int s = 128; s > 0; s >>= 1) { if (tid < s) red[tid] += red[tid + s]; __syncthreads(); }
    float inv = 1.0f / red[0];
    #pragma unroll
    for (int i = 0; i < 8; i++) pb[tid + i * 256] = f2bf(vals[i] * inv);
}

// ---------------- attnv: partial[kz] = p_chunk @ v_chunk, bf16 MFMA ----------------
// grid (N/32, H, KS), block 256 (4 waves, one 16x16 tile each)
__global__ void attnv_mfma_kernel(const float* __restrict__ scores,
                                  const unsigned short* __restrict__ vbt,
                                  float* __restrict__ partial) {
    __shared__ __align__(16) unsigned short ps[32][264];
    __shared__ __align__(16) unsigned short vt[32][264];
    int tid = threadIdx.x;
    int i0 = blockIdx.x * 32;
    int hh = blockIdx.y;
    int kz = blockIdx.z;
    int k0 = kz * KCHUNK;
    #pragma unroll
    for (int it = 0; it < 4; it++) {
        int idx = it * 256 + tid;
        int row = idx >> 5, g = idx & 31;
        const unsigned short* prow =
            (const unsigned short*)(scores + ((size_t)(hh * N_NODES + i0 + row)) * N_NODES);
        *(uint4*)&ps[row][g * 8] = *(const uint4*)&prow[k0 + g * 8];
        *(uint4*)&vt[row][g * 8] =
            *(const uint4*)&vbt[(size_t)(hh * DH + row) * N_NODES + k0 + g * 8];
    }
    __syncthreads();
    int w = tid >> 6, lane = tid & 63;
    int rowg = (w & 1) * 16, colg = (w >> 1) * 16;
    int m = lane & 15, quad = lane >> 4;
    f32x4 acc = {0.f, 0.f, 0.f, 0.f};
    #pragma unroll
    for (int ksi = 0; ksi < KCHUNK / 32; ksi++) {
        short8 a = *(const short8*)&ps[rowg + m][ksi * 32 + quad * 8];
        short8 b = *(const short8*)&vt[colg + m][ksi * 32 + quad * 8];
        acc = __builtin_amdgcn_mfma_f32_16x16x32_bf16(a, b, acc, 0, 0, 0);
    }
    #pragma unroll
    for (int reg = 0; reg < 4; reg++) {
        int row = i0 + rowg + quad * 4 + reg;
        int col = colg + m;
        partial[((size_t)kz * N_NODES + row) * D_MODEL + hh * DH + col] = acc[reg];
    }
}

// ---------------- reduce split-K partials ----------------
__global__ void reduce_kernel(const float* __restrict__ partial, float* __restrict__ aout) {
    int i = blockIdx.x * 256 + threadIdx.x;
    float s = 0.f;
    #pragma unroll
    for (int kz = 0; kz < KS; kz++) s += partial[(size_t)kz * N_NODES * D_MODEL + i];
    aout[i] = s;
}

extern "C" void kernel_launch(void* const* d_in, const int* in_sizes, int n_in,
                              void* d_out, int out_size, void* d_ws, size_t ws_size,
                              hipStream_t stream) {
    const float* x          = (const float*)d_in[0];
    const int*   edge_index = (const int*)d_in[1];
    const int*   edge_types = (const int*)d_in[2];
    const float* pos        = (const float*)d_in[3];
    const float* W_emb      = (const float*)d_in[4];
    const float* b_emb      = (const float*)d_in[5];
    const float* Wq         = (const float*)d_in[6];
    const float* Wk         = (const float*)d_in[7];
    const float* Wv         = (const float*)d_in[8];
    const float* Wo         = (const float*)d_in[9];
    const float* bq         = (const float*)d_in[10];
    const float* bk         = (const float*)d_in[11];
    const float* bv         = (const float*)d_in[12];
    const float* bo         = (const float*)d_in[13];
    const float* spd_table  = (const float*)d_in[14];
    const float* edge_table = (const float*)d_in[15];
    const float* din_emb    = (const float*)d_in[16];
    const float* dout_emb   = (const float*)d_in[17];
    const float* ln1_g      = (const float*)d_in[18];
    const float* ln1_b      = (const float*)d_in[19];
    const float* ln2_g      = (const float*)d_in[20];
    const float* ln2_b      = (const float*)d_in[21];
    const float* W1         = (const float*)d_in[22];
    const float* b1         = (const float*)d_in[23];
    const float* W2         = (const float*)d_in[24];
    const float* b2         = (const float*)d_in[25];
    const float* W_out      = (const float*)d_in[26];
    const float* b_out      = (const float*)d_in[27];
    float* out = (float*)d_out;

    char* base = (char*)d_ws;
    int* deg_out = (int*)base;              base += (size_t)N_NODES * 4;
    int* deg_in  = (int*)base;              base += (size_t)N_NODES * 4;
    float* h     = (float*)base;            base += (size_t)N_NODES * D_MODEL * 4;
    float* xn    = (float*)base;            base += (size_t)N_NODES * D_MODEL * 4;
    float* q     = (float*)base;            base += (size_t)N_NODES * D_MODEL * 4;
    float* k     = (float*)base;            base += (size_t)N_NODES * D_MODEL * 4;
    float* v     = (float*)base;            base += (size_t)N_NODES * D_MODEL * 4;
    float* aout  = (float*)base;            base += (size_t)N_NODES * D_MODEL * 4;
    float* ffn   = (float*)base;            base += (size_t)N_NODES * D_FF * 4;
    unsigned short* vbt = (unsigned short*)base; base += (size_t)D_MODEL * N_NODES * 2;
    float* partial = (float*)base;          base += (size_t)KS * N_NODES * D_MODEL * 4;
    float* scores = (float*)base;           base += (size_t)NHEAD * N_NODES * N_NODES * 4;

    hipMemsetAsync(deg_out, 0, (size_t)N_NODES * 4 * 2, stream);
    degree_kernel<<<NEDGE / 256, 256, 0, stream>>>(edge_index, deg_out, deg_in);

    gemm_kernel<0, false><<<dim3(D_MODEL / 64, N_NODES / 32), 256, 0, stream>>>(
        x, W_emb, b_emb, h, N_NODES, D_MODEL, D_FEAT);

    for (int l = 0; l < NLAYER; l++) {
        const float* Wq_l = Wq + (size_t)l * D_MODEL * D_MODEL;
        const float* Wk_l = Wk + (size_t)l * D_MODEL * D_MODEL;
        const float* Wv_l = Wv + (size_t)l * D_MODEL * D_MODEL;
        const float* Wo_l = Wo + (size_t)l * D_MODEL * D_MODEL;
        const float* W1_l = W1 + (size_t)l * D_MODEL * D_FF;
        const float* W2_l = W2 + (size_t)l * D_FF * D_MODEL;

        centrality_kernel<<<N_NODES * D_MODEL / 256, 256, 0, stream>>>(
            h, din_emb + (size_t)l * (MAXDEG + 1) * D_MODEL,
            dout_emb + (size_t)l * (MAXDEG + 1) * D_MODEL, deg_in, deg_out);

        layernorm_kernel<<<N_NODES, 256, 0, stream>>>(h, ln1_g + l * D_MODEL, ln1_b + l * D_MODEL, xn);

        qkv_gemm_kernel<<<dim3(768 / 64, N_NODES / 32), 256, 0, stream>>>(
            xn, Wq_l, Wk_l, Wv_l, bq + l * D_MODEL, bk + l * D_MODEL, bv + l * D_MODEL, q, k, v);

        vbt_cast_kernel<<<dim3(D_MODEL / 32, N_NODES / 32), 256, 0, stream>>>(v, vbt);

        scores_mfma_kernel<<<dim3(N_NODES / 64, N_NODES / 64, NHEAD), 256, 0, stream>>>(
            q, k, pos, spd_table + (size_t)l * 11 * NHEAD, scores);

        edge_bias_kernel<<<NEDGE * NHEAD / 256, 256, 0, stream>>>(
            edge_index, edge_types, edge_table + (size_t)l * 8 * NHEAD, scores);

        softmax_kernel<<<NHEAD * N_NODES, 256, 0, stream>>>(scores);

        attnv_mfma_kernel<<<dim3(N_NODES / 32, NHEAD, KS), 256, 0, stream>>>(scores, vbt, partial);

        reduce_kernel<<<N_NODES * D_MODEL / 256, 256, 0, stream>>>(partial, aout);

        gemm_kernel<0, true><<<dim3(D_MODEL / 64, N_NODES / 32), 256, 0, stream>>>(
            aout, Wo_l, bo + l * D_MODEL, h, N_NODES, D_MODEL, D_MODEL);

        layernorm_kernel<<<N_NODES, 256, 0, stream>>>(h, ln2_g + l * D_MODEL, ln2_b + l * D_MODEL, xn);

        gemm_kernel<1, false><<<dim3(D_FF / 64, N_NODES / 32), 256, 0, stream>>>(
            xn, W1_l, b1 + l * D_FF, ffn, N_NODES, D_FF, D_MODEL);

        gemm_kernel<0, true><<<dim3(D_MODEL / 64, N_NODES / 32), 256, 0, stream>>>(
            ffn, W2_l, b2 + l * D_MODEL, h, N_NODES, D_MODEL, D_FF);
    }

    gemm_kernel<0, false><<<dim3(D_OUT / 64, N_NODES / 32), 256, 0, stream>>>(
        h, W_out, b_out, out, N_NODES, D_OUT, D_MODEL);
}

// Round 3
// 453.521 us; speedup vs baseline: 3.1707x; 1.3143x over previous
//
#include <hip/hip_runtime.h>
#include <math.h>

#define N_NODES 2048
#define D_MODEL 256
#define D_FEAT 128
#define NHEAD 8
#define DH 32
#define NLAYER 2
#define NEDGE 65536
#define D_FF 1024
#define D_OUT 128
#define MAXDEG 512
#define KS 8           // split-K factor for attnv
#define KCHUNK 256     // K per attnv block

typedef __attribute__((ext_vector_type(8))) short short8;
typedef __attribute__((ext_vector_type(4))) float f32x4;
typedef __attribute__((ext_vector_type(4))) unsigned short u16x4;

__device__ __forceinline__ unsigned short f2bf(float f) {
    unsigned u = __float_as_uint(f);
    unsigned r = (u + 0x7FFFu + ((u >> 16) & 1u)) >> 16;
    return (unsigned short)r;
}

// ---------------- degree count ----------------
__global__ void degree_kernel(const int* __restrict__ edge_index,
                              int* __restrict__ deg_out, int* __restrict__ deg_in) {
    int e = blockIdx.x * 256 + threadIdx.x;
    if (e < NEDGE) {
        atomicAdd(&deg_out[edge_index[e]], 1);
        atomicAdd(&deg_in[edge_index[NEDGE + e]], 1);
    }
}

// ---------------- centrality add ----------------
__global__ void centrality_kernel(float* __restrict__ h,
                                  const float* __restrict__ din_l,
                                  const float* __restrict__ dout_l,
                                  const int* __restrict__ deg_in,
                                  const int* __restrict__ deg_out) {
    int idx = blockIdx.x * 256 + threadIdx.x;
    int row = idx >> 8;
    int c = idx & 255;
    int di = min(deg_in[row], MAXDEG);
    int dn = min(deg_out[row], MAXDEG);
    h[idx] += din_l[di * D_MODEL + c] + dout_l[dn * D_MODEL + c];
}

// ---------------- layernorm: fp32 in -> bf16 out ----------------
__global__ void layernorm_kernel(const float* __restrict__ x,
                                 const float* __restrict__ g,
                                 const float* __restrict__ b,
                                 unsigned short* __restrict__ y) {
    int row = blockIdx.x;
    int tid = threadIdx.x;
    float v = x[row * D_MODEL + tid];
    __shared__ float red[256];
    red[tid] = v; __syncthreads();
    for (int s = 128; s > 0; s >>= 1) { if (tid < s) red[tid] += red[tid + s]; __syncthreads(); }
    float mu = red[0] * (1.0f / D_MODEL);
    __syncthreads();
    float d = v - mu;
    red[tid] = d * d; __syncthreads();
    for (int s = 128; s > 0; s >>= 1) { if (tid < s) red[tid] += red[tid + s]; __syncthreads(); }
    float rstd = rsqrtf(red[0] * (1.0f / D_MODEL) + 1e-5f);
    y[row * D_MODEL + tid] = f2bf(d * rstd * g[tid] + b[tid]);
}

// ---------------- generic fp32 -> bf16 cast (vectorized x4) ----------------
__global__ void cast_kernel(const float* __restrict__ src, unsigned short* __restrict__ dst) {
    int i = blockIdx.x * 256 + threadIdx.x;
    float4 p = *(const float4*)&src[(size_t)i * 4];
    u16x4 o;
    o[0] = f2bf(p.x); o[1] = f2bf(p.y); o[2] = f2bf(p.z); o[3] = f2bf(p.w);
    *(u16x4*)&dst[(size_t)i * 4] = o;
}

// ---------------- SPD bucket table: pos -> uint8 bucket ----------------
__global__ void bucket_kernel(const float* __restrict__ pos, unsigned char* __restrict__ bucket) {
    int i = blockIdx.x * 256 + threadIdx.x;   // N*N/4
    float4 p = *(const float4*)&pos[(size_t)i * 4];
    unsigned b0 = (unsigned)fminf(fmaxf(p.x * 10.f + 0.5f, 0.f), 10.f);
    unsigned b1 = (unsigned)fminf(fmaxf(p.y * 10.f + 0.5f, 0.f), 10.f);
    unsigned b2 = (unsigned)fminf(fmaxf(p.z * 10.f + 0.5f, 0.f), 10.f);
    unsigned b3 = (unsigned)fminf(fmaxf(p.w * 10.f + 0.5f, 0.f), 10.f);
    ((unsigned*)bucket)[i] = b0 | (b1 << 8) | (b2 << 16) | (b3 << 24);
}

// ---------------- weight transpose+cast tile helper: W[K][Nc] fp32 -> Wt[Nc][K] bf16 ----------------
__device__ __forceinline__ void wt_tile(const float* __restrict__ W, unsigned short* __restrict__ Wt,
                                        int K, int Nc, int n0, int k0, int tid,
                                        unsigned short (*tile)[33]) {
    int r = tid >> 3, cg = (tid & 7) * 4;
    float4 w4 = *(const float4*)&W[(size_t)(k0 + r) * Nc + n0 + cg];
    tile[r][cg + 0] = f2bf(w4.x); tile[r][cg + 1] = f2bf(w4.y);
    tile[r][cg + 2] = f2bf(w4.z); tile[r][cg + 3] = f2bf(w4.w);
    __syncthreads();
    int c = tid >> 3, rg = (tid & 7) * 4;
    u16x4 o;
    #pragma unroll
    for (int j = 0; j < 4; j++) o[j] = tile[rg + j][c];
    *(u16x4*)&Wt[(size_t)(n0 + c) * K + k0 + rg] = o;
}

// qkv+o weights: grid (8,8, L*4); qkvt layout [L][768][256], wot [L][256][256]
__global__ void wt_qkvo_kernel(const float* __restrict__ Wq, const float* __restrict__ Wk,
                               const float* __restrict__ Wv, const float* __restrict__ Wo,
                               unsigned short* __restrict__ qkvt, unsigned short* __restrict__ wot) {
    __shared__ unsigned short tile[32][33];
    int z = blockIdx.z, l = z >> 2, which = z & 3;
    const float* W = (which == 0 ? Wq : which == 1 ? Wk : which == 2 ? Wv : Wo) + (size_t)l * 65536;
    unsigned short* dst = (which < 3) ? qkvt + (size_t)l * 196608 + which * 65536
                                      : wot + (size_t)l * 65536;
    wt_tile(W, dst, 256, 256, blockIdx.x * 32, blockIdx.y * 32, threadIdx.x, tile);
}

__global__ void wt_ffn1_kernel(const float* __restrict__ W1, unsigned short* __restrict__ w1t) {
    __shared__ unsigned short tile[32][33];
    int l = blockIdx.z;
    wt_tile(W1 + (size_t)l * D_MODEL * D_FF, w1t + (size_t)l * D_MODEL * D_FF,
            D_MODEL, D_FF, blockIdx.x * 32, blockIdx.y * 32, threadIdx.x, tile);
}

__global__ void wt_ffn2_kernel(const float* __restrict__ W2, unsigned short* __restrict__ w2t) {
    __shared__ unsigned short tile[32][33];
    int l = blockIdx.z;
    wt_tile(W2 + (size_t)l * D_FF * D_MODEL, w2t + (size_t)l * D_FF * D_MODEL,
            D_FF, D_MODEL, blockIdx.x * 32, blockIdx.y * 32, threadIdx.x, tile);
}

__global__ void wt_small_kernel(const float* __restrict__ W_emb, const float* __restrict__ W_out,
                                unsigned short* __restrict__ wembt, unsigned short* __restrict__ woutt) {
    __shared__ unsigned short tile[32][33];
    if (blockIdx.z == 0) {
        if (blockIdx.y >= 4) return;   // K=128
        wt_tile(W_emb, wembt, D_FEAT, D_MODEL, blockIdx.x * 32, blockIdx.y * 32, threadIdx.x, tile);
    } else {
        if (blockIdx.x >= 4) return;   // Nc=128
        wt_tile(W_out, woutt, D_MODEL, D_OUT, blockIdx.x * 32, blockIdx.y * 32, threadIdx.x, tile);
    }
}

__global__ void bias_stack_kernel(const float* __restrict__ bq, const float* __restrict__ bk,
                                  const float* __restrict__ bv, float* __restrict__ bqkv) {
    int i = blockIdx.x * 256 + threadIdx.x;    // L*768
    int l = i / 768, j = i % 768;
    const float* src = j < 256 ? bq : j < 512 ? bk : bv;
    bqkv[i] = src[l * 256 + (j & 255)];
}

// ---------------- bf16 MFMA GEMM: C[M][Nc] = A[M][K] @ Wt[Nc][K]^T + bias ----------------
// tile 32(M) x 64(N), block 256 = 4 waves, each wave 16 rows x 32 cols
template <int ACT, bool RESID, bool OUTBF16>
__global__ void gemm_mfma_kernel(const unsigned short* __restrict__ A,
                                 const unsigned short* __restrict__ Wt,
                                 const float* __restrict__ bias,
                                 float* __restrict__ C, unsigned short* __restrict__ Cb,
                                 int Nc, int K) {
    __shared__ __align__(16) unsigned short As[32][72];
    __shared__ __align__(16) unsigned short Bs[64][72];
    int tid = threadIdx.x;
    int m0 = blockIdx.y * 32, n0 = blockIdx.x * 64;
    int w = tid >> 6, lane = tid & 63;
    int rg = (w & 1) * 16, cg = (w >> 1) * 32;
    int m = lane & 15, quad = lane >> 4;
    f32x4 acc[2] = {{0.f, 0.f, 0.f, 0.f}, {0.f, 0.f, 0.f, 0.f}};
    int ar = tid >> 3, ac = (tid & 7) * 8;
    for (int k0 = 0; k0 < K; k0 += 64) {
        *(uint4*)&As[ar][ac] = *(const uint4*)&A[(size_t)(m0 + ar) * K + k0 + ac];
        *(uint4*)&Bs[ar][ac] = *(const uint4*)&Wt[(size_t)(n0 + ar) * K + k0 + ac];
        *(uint4*)&Bs[ar + 32][ac] = *(const uint4*)&Wt[(size_t)(n0 + 32 + ar) * K + k0 + ac];
        __syncthreads();
        #pragma unroll
        for (int ks = 0; ks < 2; ks++) {
            short8 a = *(const short8*)&As[rg + m][ks * 32 + quad * 8];
            #pragma unroll
            for (int t = 0; t < 2; t++) {
                short8 b = *(const short8*)&Bs[cg + t * 16 + m][ks * 32 + quad * 8];
                acc[t] = __builtin_amdgcn_mfma_f32_16x16x32_bf16(a, b, acc[t], 0, 0, 0);
            }
        }
        __syncthreads();
    }
    #pragma unroll
    for (int t = 0; t < 2; t++) {
        #pragma unroll
        for (int reg = 0; reg < 4; reg++) {
            int row = m0 + rg + quad * 4 + reg;
            int col = n0 + cg + t * 16 + m;
            float val = acc[t][reg] + bias[col];
            if (ACT == 1) val = val * 0.5f * (1.0f + erff(val * 0.7071067811865476f));
            size_t idx = (size_t)row * Nc + col;
            if (RESID) val += C[idx];
            if (OUTBF16) Cb[idx] = f2bf(val);
            else C[idx] = val;
        }
    }
}

// ---------------- transpose v slice of qkvb -> vbt (bf16 [D][N]) ----------------
__global__ void vbt_cast_kernel(const unsigned short* __restrict__ qkvb,
                                unsigned short* __restrict__ vbt) {
    __shared__ unsigned short tile[32][33];
    int c0 = blockIdx.x * 32, r0 = blockIdx.y * 32;
    int tid = threadIdx.x;
    int r = tid >> 3, cg = (tid & 7) * 4;
    u16x4 v4 = *(const u16x4*)&qkvb[(size_t)(r0 + r) * 768 + 512 + c0 + cg];
    tile[r][cg + 0] = v4[0]; tile[r][cg + 1] = v4[1];
    tile[r][cg + 2] = v4[2]; tile[r][cg + 3] = v4[3];
    __syncthreads();
    int c = tid >> 3, rg = (tid & 7) * 4;
    u16x4 o;
    #pragma unroll
    for (int j = 0; j < 4; j++) o[j] = tile[rg + j][c];
    *(u16x4*)&vbt[(size_t)(c0 + c) * N_NODES + r0 + rg] = o;
}

// ---------------- scores = (q@k^T)*scale + spd bias, bf16 MFMA ----------------
// grid (N/64, N/64, H), block 256 (4 waves); each wave: 16 rows x 64 cols
__global__ void scores_mfma_kernel(const unsigned short* __restrict__ qkvb,
                                   const unsigned char* __restrict__ bucket,
                                   const float* __restrict__ spd_l,
                                   float* __restrict__ scores) {
    __shared__ __align__(16) unsigned short qs[64][40];
    __shared__ __align__(16) unsigned short ks[64][40];
    __shared__ float spd[11 * NHEAD];
    int tid = threadIdx.x;
    int hh = blockIdx.z;
    int i0 = blockIdx.y * 64, j0 = blockIdx.x * 64;
    if (tid < 11 * NHEAD) spd[tid] = spd_l[tid];
    {
        int r = tid >> 2, g = (tid & 3) * 8;
        *(uint4*)&qs[r][g] = *(const uint4*)&qkvb[(size_t)(i0 + r) * 768 + hh * DH + g];
        *(uint4*)&ks[r][g] = *(const uint4*)&qkvb[(size_t)(j0 + r) * 768 + 256 + hh * DH + g];
    }
    __syncthreads();
    int w = tid >> 6, lane = tid & 63;
    int wrow = w * 16;
    int m = lane & 15, quad = lane >> 4;
    short8 av = *(const short8*)&qs[wrow + m][quad * 8];
    f32x4 acc[4];
    #pragma unroll
    for (int t = 0; t < 4; t++) {
        f32x4 z = {0.f, 0.f, 0.f, 0.f};
        short8 bv = *(const short8*)&ks[t * 16 + m][quad * 8];
        acc[t] = __builtin_amdgcn_mfma_f32_16x16x32_bf16(av, bv, z, 0, 0, 0);
    }
    const float scale = 0.17677669529663687f;
    #pragma unroll
    for (int t = 0; t < 4; t++) {
        #pragma unroll
        for (int reg = 0; reg < 4; reg++) {
            int row = i0 + wrow + quad * 4 + reg;
            int col = j0 + t * 16 + m;
            unsigned char bu = bucket[(size_t)row * N_NODES + col];
            scores[((size_t)hh * N_NODES + row) * N_NODES + col] =
                acc[t][reg] * scale + spd[bu * NHEAD + hh];
        }
    }
}

// ---------------- edge bias scatter-add (fp32 atomics) ----------------
__global__ void edge_bias_kernel(const int* __restrict__ edge_index,
                                 const int* __restrict__ edge_types,
                                 const float* __restrict__ et_l,
                                 float* __restrict__ scores) {
    int idx = blockIdx.x * 256 + threadIdx.x;
    int e = idx >> 3;
    int hh = idx & 7;
    if (e < NEDGE) {
        int s = edge_index[e];
        int d2 = edge_index[NEDGE + e];
        float val = et_l[edge_types[e] * NHEAD + hh];
        atomicAdd(&scores[((size_t)hh * N_NODES + s) * N_NODES + d2], val);
    }
}

// ---------------- softmax: fp32 row in, bf16 row out (in place, first half) ----------------
__global__ void softmax_kernel(float* __restrict__ scores) {
    float* p = scores + (size_t)blockIdx.x * N_NODES;
    unsigned short* pb = (unsigned short*)p;
    int tid = threadIdx.x;
    float vals[8];
    float m = -INFINITY;
    #pragma unroll
    for (int i = 0; i < 8; i++) { vals[i] = p[tid + i * 256]; m = fmaxf(m, vals[i]); }
    __shared__ float red[256];
    red[tid] = m; __syncthreads();
    for (int s = 128; s > 0; s >>= 1) { if (tid < s) red[tid] = fmaxf(red[tid], red[tid + s]); __syncthreads(); }
    m = red[0]; __syncthreads();
    float sum = 0.f;
    #pragma unroll
    for (int i = 0; i < 8; i++) { vals[i] = expf(vals[i] - m); sum += vals[i]; }
    red[tid] = sum; __syncthreads();
    for (int s = 128; s > 0; s >>= 1) { if (tid < s) red[tid] += red[tid + s]; __syncthreads(); }
    float inv = 1.0f / red[0];
    #pragma unroll
    for (int i = 0; i < 8; i++) pb[tid + i * 256] = f2bf(vals[i] * inv);
}

// ---------------- attnv: partial[kz] = p_chunk @ v_chunk, bf16 MFMA ----------------
__global__ void attnv_mfma_kernel(const float* __restrict__ scores,
                                  const unsigned short* __restrict__ vbt,
                                  float* __restrict__ partial) {
    __shared__ __align__(16) unsigned short ps[32][264];
    __shared__ __align__(16) unsigned short vt[32][264];
    int tid = threadIdx.x;
    int i0 = blockIdx.x * 32;
    int hh = blockIdx.y;
    int kz = blockIdx.z;
    int k0 = kz * KCHUNK;
    #pragma unroll
    for (int it = 0; it < 4; it++) {
        int idx = it * 256 + tid;
        int row = idx >> 5, g = idx & 31;
        const unsigned short* prow =
            (const unsigned short*)(scores + ((size_t)(hh * N_NODES + i0 + row)) * N_NODES);
        *(uint4*)&ps[row][g * 8] = *(const uint4*)&prow[k0 + g * 8];
        *(uint4*)&vt[row][g * 8] =
            *(const uint4*)&vbt[(size_t)(hh * DH + row) * N_NODES + k0 + g * 8];
    }
    __syncthreads();
    int w = tid >> 6, lane = tid & 63;
    int rowg = (w & 1) * 16, colg = (w >> 1) * 16;
    int m = lane & 15, quad = lane >> 4;
    f32x4 acc = {0.f, 0.f, 0.f, 0.f};
    #pragma unroll
    for (int ksi = 0; ksi < KCHUNK / 32; ksi++) {
        short8 a = *(const short8*)&ps[rowg + m][ksi * 32 + quad * 8];
        short8 b = *(const short8*)&vt[colg + m][ksi * 32 + quad * 8];
        acc = __builtin_amdgcn_mfma_f32_16x16x32_bf16(a, b, acc, 0, 0, 0);
    }
    #pragma unroll
    for (int reg = 0; reg < 4; reg++) {
        int row = i0 + rowg + quad * 4 + reg;
        int col = colg + m;
        partial[((size_t)kz * N_NODES + row) * D_MODEL + hh * DH + col] = acc[reg];
    }
}

// ---------------- reduce split-K partials -> bf16 ----------------
__global__ void reduce_kernel(const float* __restrict__ partial, unsigned short* __restrict__ aoutb) {
    int i = blockIdx.x * 256 + threadIdx.x;
    float s = 0.f;
    #pragma unroll
    for (int kz = 0; kz < KS; kz++) s += partial[(size_t)kz * N_NODES * D_MODEL + i];
    aoutb[i] = f2bf(s);
}

extern "C" void kernel_launch(void* const* d_in, const int* in_sizes, int n_in,
                              void* d_out, int out_size, void* d_ws, size_t ws_size,
                              hipStream_t stream) {
    const float* x          = (const float*)d_in[0];
    const int*   edge_index = (const int*)d_in[1];
    const int*   edge_types = (const int*)d_in[2];
    const float* pos        = (const float*)d_in[3];
    const float* W_emb      = (const float*)d_in[4];
    const float* b_emb      = (const float*)d_in[5];
    const float* Wq         = (const float*)d_in[6];
    const float* Wk         = (const float*)d_in[7];
    const float* Wv         = (const float*)d_in[8];
    const float* Wo         = (const float*)d_in[9];
    const float* bq         = (const float*)d_in[10];
    const float* bk         = (const float*)d_in[11];
    const float* bv         = (const float*)d_in[12];
    const float* bo         = (const float*)d_in[13];
    const float* spd_table  = (const float*)d_in[14];
    const float* edge_table = (const float*)d_in[15];
    const float* din_emb    = (const float*)d_in[16];
    const float* dout_emb   = (const float*)d_in[17];
    const float* ln1_g      = (const float*)d_in[18];
    const float* ln1_b      = (const float*)d_in[19];
    const float* ln2_g      = (const float*)d_in[20];
    const float* ln2_b      = (const float*)d_in[21];
    const float* W1         = (const float*)d_in[22];
    const float* b1         = (const float*)d_in[23];
    const float* W2         = (const float*)d_in[24];
    const float* b2         = (const float*)d_in[25];
    const float* W_out      = (const float*)d_in[26];
    const float* b_out      = (const float*)d_in[27];
    float* out = (float*)d_out;

    char* base = (char*)d_ws;
    int* deg_out = (int*)base;                    base += (size_t)N_NODES * 4;
    int* deg_in  = (int*)base;                    base += (size_t)N_NODES * 4;
    float* h     = (float*)base;                  base += (size_t)N_NODES * D_MODEL * 4;
    unsigned short* hb   = (unsigned short*)base; base += (size_t)N_NODES * D_MODEL * 2;
    unsigned short* xb   = (unsigned short*)base; base += (size_t)N_NODES * D_MODEL * 2;
    unsigned short* xb0  = (unsigned short*)base; base += (size_t)N_NODES * D_FEAT * 2;
    unsigned short* qkvb = (unsigned short*)base; base += (size_t)N_NODES * 768 * 2;
    unsigned short* vbt  = (unsigned short*)base; base += (size_t)D_MODEL * N_NODES * 2;
    unsigned short* aoutb = (unsigned short*)base; base += (size_t)N_NODES * D_MODEL * 2;
    unsigned short* ffnb = (unsigned short*)base; base += (size_t)N_NODES * D_FF * 2;
    float* partial = (float*)base;                base += (size_t)KS * N_NODES * D_MODEL * 4;
    unsigned char* bucket = (unsigned char*)base; base += (size_t)N_NODES * N_NODES;
    unsigned short* qkvt = (unsigned short*)base; base += (size_t)NLAYER * 768 * D_MODEL * 2;
    unsigned short* wot  = (unsigned short*)base; base += (size_t)NLAYER * D_MODEL * D_MODEL * 2;
    unsigned short* w1t  = (unsigned short*)base; base += (size_t)NLAYER * D_MODEL * D_FF * 2;
    unsigned short* w2t  = (unsigned short*)base; base += (size_t)NLAYER * D_FF * D_MODEL * 2;
    unsigned short* wembt = (unsigned short*)base; base += (size_t)D_FEAT * D_MODEL * 2;
    unsigned short* woutt = (unsigned short*)base; base += (size_t)D_MODEL * D_OUT * 2;
    float* bqkv = (float*)base;                   base += (size_t)NLAYER * 768 * 4;
    float* scores = (float*)base;                 base += (size_t)NHEAD * N_NODES * N_NODES * 4;

    hipMemsetAsync(deg_out, 0, (size_t)N_NODES * 4 * 2, stream);
    degree_kernel<<<NEDGE / 256, 256, 0, stream>>>(edge_index, deg_out, deg_in);

    // ---- one-time prep: weight transpose+cast, bias stack, bucket table, x cast ----
    wt_qkvo_kernel<<<dim3(8, 8, NLAYER * 4), 256, 0, stream>>>(Wq, Wk, Wv, Wo, qkvt, wot);
    wt_ffn1_kernel<<<dim3(D_FF / 32, D_MODEL / 32, NLAYER), 256, 0, stream>>>(W1, w1t);
    wt_ffn2_kernel<<<dim3(D_MODEL / 32, D_FF / 32, NLAYER), 256, 0, stream>>>(W2, w2t);
    wt_small_kernel<<<dim3(8, 8, 2), 256, 0, stream>>>(W_emb, W_out, wembt, woutt);
    bias_stack_kernel<<<NLAYER * 768 / 256, 256, 0, stream>>>(bq, bk, bv, bqkv);
    bucket_kernel<<<(size_t)N_NODES * N_NODES / 4 / 256, 256, 0, stream>>>(pos, bucket);
    cast_kernel<<<N_NODES * D_FEAT / 4 / 256, 256, 0, stream>>>(x, xb0);

    // embed: h = x @ W_emb + b_emb
    gemm_mfma_kernel<0, false, false><<<dim3(D_MODEL / 64, N_NODES / 32), 256, 0, stream>>>(
        xb0, wembt, b_emb, h, nullptr, D_MODEL, D_FEAT);

    for (int l = 0; l < NLAYER; l++) {
        centrality_kernel<<<N_NODES * D_MODEL / 256, 256, 0, stream>>>(
            h, din_emb + (size_t)l * (MAXDEG + 1) * D_MODEL,
            dout_emb + (size_t)l * (MAXDEG + 1) * D_MODEL, deg_in, deg_out);

        layernorm_kernel<<<N_NODES, 256, 0, stream>>>(h, ln1_g + l * D_MODEL, ln1_b + l * D_MODEL, xb);

        gemm_mfma_kernel<0, false, true><<<dim3(768 / 64, N_NODES / 32), 256, 0, stream>>>(
            xb, qkvt + (size_t)l * 768 * D_MODEL, bqkv + l * 768, nullptr, qkvb, 768, D_MODEL);

        vbt_cast_kernel<<<dim3(D_MODEL / 32, N_NODES / 32), 256, 0, stream>>>(qkvb, vbt);

        scores_mfma_kernel<<<dim3(N_NODES / 64, N_NODES / 64, NHEAD), 256, 0, stream>>>(
            qkvb, bucket, spd_table + (size_t)l * 11 * NHEAD, scores);

        edge_bias_kernel<<<NEDGE * NHEAD / 256, 256, 0, stream>>>(
            edge_index, edge_types, edge_table + (size_t)l * 8 * NHEAD, scores);

        softmax_kernel<<<NHEAD * N_NODES, 256, 0, stream>>>(scores);

        attnv_mfma_kernel<<<dim3(N_NODES / 32, NHEAD, KS), 256, 0, stream>>>(scores, vbt, partial);

        reduce_kernel<<<N_NODES * D_MODEL / 256, 256, 0, stream>>>(partial, aoutb);

        gemm_mfma_kernel<0, true, false><<<dim3(D_MODEL / 64, N_NODES / 32), 256, 0, stream>>>(
            aoutb, wot + (size_t)l * D_MODEL * D_MODEL, bo + l * D_MODEL, h, nullptr, D_MODEL, D_MODEL);

        layernorm_kernel<<<N_NODES, 256, 0, stream>>>(h, ln2_g + l * D_MODEL, ln2_b + l * D_MODEL, xb);

        gemm_mfma_kernel<1, false, true><<<dim3(D_FF / 64, N_NODES / 32), 256, 0, stream>>>(
            xb, w1t + (size_t)l * D_MODEL * D_FF, b1 + l * D_FF, nullptr, ffnb, D_FF, D_MODEL);

        gemm_mfma_kernel<0, true, false><<<dim3(D_MODEL / 64, N_NODES / 32), 256, 0, stream>>>(
            ffnb, w2t + (size_t)l * D_FF * D_MODEL, b2 + l * D_MODEL, h, nullptr, D_MODEL, D_FF);
    }

    cast_kernel<<<N_NODES * D_MODEL / 4 / 256, 256, 0, stream>>>(h, hb);
    gemm_mfma_kernel<0, false, false><<<dim3(D_OUT / 64, N_NODES / 32), 256, 0, stream>>>(
        hb, woutt, b_out, out, nullptr, D_OUT, D_MODEL);
}

// Round 4
// 447.504 us; speedup vs baseline: 3.2133x; 1.0134x over previous
//
#include <hip/hip_runtime.h>
#include <math.h>

#define N_NODES 2048
#define D_MODEL 256
#define D_FEAT 128
#define NHEAD 8
#define DH 32
#define NLAYER 2
#define NEDGE 65536
#define D_FF 1024
#define D_OUT 128
#define MAXDEG 512

typedef __attribute__((ext_vector_type(8))) short short8;
typedef __attribute__((ext_vector_type(4))) float f32x4;
typedef __attribute__((ext_vector_type(4))) unsigned short u16x4;

__device__ __forceinline__ unsigned short f2bf(float f) {
    unsigned u = __float_as_uint(f);
    unsigned r = (u + 0x7FFFu + ((u >> 16) & 1u)) >> 16;
    return (unsigned short)r;
}

// ---------------- degree count ----------------
__global__ void degree_kernel(const int* __restrict__ edge_index,
                              int* __restrict__ deg_out, int* __restrict__ deg_in) {
    int e = blockIdx.x * 256 + threadIdx.x;
    if (e < NEDGE) {
        atomicAdd(&deg_out[edge_index[e]], 1);
        atomicAdd(&deg_in[edge_index[NEDGE + e]], 1);
    }
}

// ---------------- centrality add ----------------
__global__ void centrality_kernel(float* __restrict__ h,
                                  const float* __restrict__ din_l,
                                  const float* __restrict__ dout_l,
                                  const int* __restrict__ deg_in,
                                  const int* __restrict__ deg_out) {
    int idx = blockIdx.x * 256 + threadIdx.x;
    int row = idx >> 8;
    int c = idx & 255;
    int di = min(deg_in[row], MAXDEG);
    int dn = min(deg_out[row], MAXDEG);
    h[idx] += din_l[di * D_MODEL + c] + dout_l[dn * D_MODEL + c];
}

// ---------------- layernorm: fp32 in -> bf16 out ----------------
__global__ void layernorm_kernel(const float* __restrict__ x,
                                 const float* __restrict__ g,
                                 const float* __restrict__ b,
                                 unsigned short* __restrict__ y) {
    int row = blockIdx.x;
    int tid = threadIdx.x;
    float v = x[row * D_MODEL + tid];
    __shared__ float red[256];
    red[tid] = v; __syncthreads();
    for (int s = 128; s > 0; s >>= 1) { if (tid < s) red[tid] += red[tid + s]; __syncthreads(); }
    float mu = red[0] * (1.0f / D_MODEL);
    __syncthreads();
    float d = v - mu;
    red[tid] = d * d; __syncthreads();
    for (int s = 128; s > 0; s >>= 1) { if (tid < s) red[tid] += red[tid + s]; __syncthreads(); }
    float rstd = rsqrtf(red[0] * (1.0f / D_MODEL) + 1e-5f);
    y[row * D_MODEL + tid] = f2bf(d * rstd * g[tid] + b[tid]);
}

// ---------------- generic fp32 -> bf16 cast ----------------
__global__ void cast_kernel(const float* __restrict__ src, unsigned short* __restrict__ dst) {
    int i = blockIdx.x * 256 + threadIdx.x;
    float4 p = *(const float4*)&src[(size_t)i * 4];
    u16x4 o;
    o[0] = f2bf(p.x); o[1] = f2bf(p.y); o[2] = f2bf(p.z); o[3] = f2bf(p.w);
    *(u16x4*)&dst[(size_t)i * 4] = o;
}

// ---------------- SPD bucket table: pos -> uint8 ----------------
__global__ void bucket_kernel(const float* __restrict__ pos, unsigned char* __restrict__ bucket) {
    int i = blockIdx.x * 256 + threadIdx.x;
    float4 p = *(const float4*)&pos[(size_t)i * 4];
    unsigned b0 = (unsigned)fminf(fmaxf(p.x * 10.f + 0.5f, 0.f), 10.f);
    unsigned b1 = (unsigned)fminf(fmaxf(p.y * 10.f + 0.5f, 0.f), 10.f);
    unsigned b2 = (unsigned)fminf(fmaxf(p.z * 10.f + 0.5f, 0.f), 10.f);
    unsigned b3 = (unsigned)fminf(fmaxf(p.w * 10.f + 0.5f, 0.f), 10.f);
    ((unsigned*)bucket)[i] = b0 | (b1 << 8) | (b2 << 16) | (b3 << 24);
}

// ---------------- edge CSR build: key = (src>>6)*2048 + dst ----------------
__global__ void edge_hist_kernel(const int* __restrict__ ei, unsigned* __restrict__ hist) {
    int e = blockIdx.x * 256 + threadIdx.x;
    if (e < NEDGE) {
        int key = (ei[e] >> 6) * 2048 + ei[NEDGE + e];
        atomicAdd(&hist[key], 1);
    }
}

__global__ void edge_scan_kernel(const unsigned* __restrict__ hist,
                                 unsigned* __restrict__ offsets, unsigned* __restrict__ cursor) {
    __shared__ unsigned csum[256];
    int t = threadIdx.x;
    unsigned s = 0;
    for (int i = 0; i < 256; i++) s += hist[t * 256 + i];
    csum[t] = s;
    __syncthreads();
    for (int off = 1; off < 256; off <<= 1) {
        unsigned vv = (t >= off) ? csum[t - off] : 0;
        __syncthreads();
        csum[t] += vv;
        __syncthreads();
    }
    unsigned run = (t == 0) ? 0 : csum[t - 1];
    for (int i = 0; i < 256; i++) {
        int idx = t * 256 + i;
        offsets[idx] = run; cursor[idx] = run;
        run += hist[idx];
    }
    if (t == 255) offsets[65536] = run;
}

__global__ void edge_scatter_kernel(const int* __restrict__ ei, const int* __restrict__ etypes,
                                    unsigned* __restrict__ cursor, unsigned* __restrict__ packed) {
    int e = blockIdx.x * 256 + threadIdx.x;
    if (e < NEDGE) {
        int src = ei[e], dst = ei[NEDGE + e];
        int key = (src >> 6) * 2048 + dst;
        unsigned pos = atomicAdd(&cursor[key], 1);
        packed[pos] = (unsigned)dst | ((unsigned)(src & 63) << 11) | ((unsigned)etypes[e] << 17);
    }
}

// ---------------- weight transpose+cast helper ----------------
__device__ __forceinline__ void wt_tile(const float* __restrict__ W, unsigned short* __restrict__ Wt,
                                        int K, int Nc, int n0, int k0, int tid,
                                        unsigned short (*tile)[33]) {
    int r = tid >> 3, cg = (tid & 7) * 4;
    float4 w4 = *(const float4*)&W[(size_t)(k0 + r) * Nc + n0 + cg];
    tile[r][cg + 0] = f2bf(w4.x); tile[r][cg + 1] = f2bf(w4.y);
    tile[r][cg + 2] = f2bf(w4.z); tile[r][cg + 3] = f2bf(w4.w);
    __syncthreads();
    int c = tid >> 3, rg = (tid & 7) * 4;
    u16x4 o;
    #pragma unroll
    for (int j = 0; j < 4; j++) o[j] = tile[rg + j][c];
    *(u16x4*)&Wt[(size_t)(n0 + c) * K + k0 + rg] = o;
}

__global__ void wt_qkvo_kernel(const float* __restrict__ Wq, const float* __restrict__ Wk,
                               const float* __restrict__ Wv, const float* __restrict__ Wo,
                               unsigned short* __restrict__ qkvt, unsigned short* __restrict__ wot) {
    __shared__ unsigned short tile[32][33];
    int z = blockIdx.z, l = z >> 2, which = z & 3;
    const float* W = (which == 0 ? Wq : which == 1 ? Wk : which == 2 ? Wv : Wo) + (size_t)l * 65536;
    unsigned short* dst = (which < 3) ? qkvt + (size_t)l * 196608 + which * 65536
                                      : wot + (size_t)l * 65536;
    wt_tile(W, dst, 256, 256, blockIdx.x * 32, blockIdx.y * 32, threadIdx.x, tile);
}

__global__ void wt_ffn1_kernel(const float* __restrict__ W1, unsigned short* __restrict__ w1t) {
    __shared__ unsigned short tile[32][33];
    int l = blockIdx.z;
    wt_tile(W1 + (size_t)l * D_MODEL * D_FF, w1t + (size_t)l * D_MODEL * D_FF,
            D_MODEL, D_FF, blockIdx.x * 32, blockIdx.y * 32, threadIdx.x, tile);
}

__global__ void wt_ffn2_kernel(const float* __restrict__ W2, unsigned short* __restrict__ w2t) {
    __shared__ unsigned short tile[32][33];
    int l = blockIdx.z;
    wt_tile(W2 + (size_t)l * D_FF * D_MODEL, w2t + (size_t)l * D_FF * D_MODEL,
            D_FF, D_MODEL, blockIdx.x * 32, blockIdx.y * 32, threadIdx.x, tile);
}

__global__ void wt_small_kernel(const float* __restrict__ W_emb, const float* __restrict__ W_out,
                                unsigned short* __restrict__ wembt, unsigned short* __restrict__ woutt) {
    __shared__ unsigned short tile[32][33];
    if (blockIdx.z == 0) {
        if (blockIdx.y >= 4) return;
        wt_tile(W_emb, wembt, D_FEAT, D_MODEL, blockIdx.x * 32, blockIdx.y * 32, threadIdx.x, tile);
    } else {
        if (blockIdx.x >= 4) return;
        wt_tile(W_out, woutt, D_MODEL, D_OUT, blockIdx.x * 32, blockIdx.y * 32, threadIdx.x, tile);
    }
}

__global__ void bias_stack_kernel(const float* __restrict__ bq, const float* __restrict__ bk,
                                  const float* __restrict__ bv, float* __restrict__ bqkv) {
    int i = blockIdx.x * 256 + threadIdx.x;
    int l = i / 768, j = i % 768;
    const float* src = j < 256 ? bq : j < 512 ? bk : bv;
    bqkv[i] = src[l * 256 + (j & 255)];
}

// ---------------- bf16 MFMA GEMM ----------------
template <int ACT, bool RESID, bool OUTBF16>
__global__ void gemm_mfma_kernel(const unsigned short* __restrict__ A,
                                 const unsigned short* __restrict__ Wt,
                                 const float* __restrict__ bias,
                                 float* __restrict__ C, unsigned short* __restrict__ Cb,
                                 int Nc, int K) {
    __shared__ __align__(16) unsigned short As[32][72];
    __shared__ __align__(16) unsigned short Bs[64][72];
    int tid = threadIdx.x;
    int m0 = blockIdx.y * 32, n0 = blockIdx.x * 64;
    int w = tid >> 6, lane = tid & 63;
    int rg = (w & 1) * 16, cg = (w >> 1) * 32;
    int m = lane & 15, quad = lane >> 4;
    f32x4 acc[2] = {{0.f, 0.f, 0.f, 0.f}, {0.f, 0.f, 0.f, 0.f}};
    int ar = tid >> 3, ac = (tid & 7) * 8;
    for (int k0 = 0; k0 < K; k0 += 64) {
        *(uint4*)&As[ar][ac] = *(const uint4*)&A[(size_t)(m0 + ar) * K + k0 + ac];
        *(uint4*)&Bs[ar][ac] = *(const uint4*)&Wt[(size_t)(n0 + ar) * K + k0 + ac];
        *(uint4*)&Bs[ar + 32][ac] = *(const uint4*)&Wt[(size_t)(n0 + 32 + ar) * K + k0 + ac];
        __syncthreads();
        #pragma unroll
        for (int ks = 0; ks < 2; ks++) {
            short8 a = *(const short8*)&As[rg + m][ks * 32 + quad * 8];
            #pragma unroll
            for (int t = 0; t < 2; t++) {
                short8 b = *(const short8*)&Bs[cg + t * 16 + m][ks * 32 + quad * 8];
                acc[t] = __builtin_amdgcn_mfma_f32_16x16x32_bf16(a, b, acc[t], 0, 0, 0);
            }
        }
        __syncthreads();
    }
    #pragma unroll
    for (int t = 0; t < 2; t++) {
        #pragma unroll
        for (int reg = 0; reg < 4; reg++) {
            int row = m0 + rg + quad * 4 + reg;
            int col = n0 + cg + t * 16 + m;
            float val = acc[t][reg] + bias[col];
            if (ACT == 1) val = val * 0.5f * (1.0f + erff(val * 0.7071067811865476f));
            size_t idx = (size_t)row * Nc + col;
            if (RESID) val += C[idx];
            if (OUTBF16) Cb[idx] = f2bf(val);
            else C[idx] = val;
        }
    }
}

// ---------------- transpose v slice of qkvb -> vbt (bf16 [DH*H][N]) ----------------
__global__ void vbt_cast_kernel(const unsigned short* __restrict__ qkvb,
                                unsigned short* __restrict__ vbt) {
    __shared__ unsigned short tile[32][33];
    int c0 = blockIdx.x * 32, r0 = blockIdx.y * 32;
    int tid = threadIdx.x;
    int r = tid >> 3, cg = (tid & 7) * 4;
    u16x4 v4 = *(const u16x4*)&qkvb[(size_t)(r0 + r) * 768 + 512 + c0 + cg];
    tile[r][cg + 0] = v4[0]; tile[r][cg + 1] = v4[1];
    tile[r][cg + 2] = v4[2]; tile[r][cg + 3] = v4[3];
    __syncthreads();
    int c = tid >> 3, rg = (tid & 7) * 4;
    u16x4 o;
    #pragma unroll
    for (int j = 0; j < 4; j++) o[j] = tile[rg + j][c];
    *(u16x4*)&vbt[(size_t)(c0 + c) * N_NODES + r0 + rg] = o;
}

// ---------------- fused flash attention: QK^T + spd + edge bias + softmax + PV ----------------
// grid (N/64, H), block 512 = 8 waves. Wave w: rows (w>>1)*16..+16 of the 64-row Q block,
// S cols (w&1)*32..+32, O d-cols (w&1)*16..+16.
__global__ __launch_bounds__(512)
void flash_attn_kernel(const unsigned short* __restrict__ qkvb,
                       const unsigned short* __restrict__ vbt,
                       const unsigned char* __restrict__ bucket,
                       const float* __restrict__ spd_l,
                       const float* __restrict__ et_l,
                       const unsigned* __restrict__ offsets,
                       const unsigned* __restrict__ packed,
                       unsigned short* __restrict__ aoutb) {
    __shared__ __align__(16) unsigned short qs[64][40];
    __shared__ __align__(16) unsigned short ks[64][40];
    __shared__ __align__(16) unsigned short vs[32][72];
    __shared__ __align__(16) float S[64][68];
    __shared__ __align__(16) unsigned short P[64][72];
    __shared__ __align__(16) unsigned char bk[64][64];
    __shared__ float pred[64][8];
    __shared__ float m_arr[64], l_arr[64], a_arr[64];
    __shared__ float spd[11], et[8];

    int tid = threadIdx.x;
    int i0 = blockIdx.x * 64;
    int hh = blockIdx.y;
    int rb = blockIdx.x;

    if (tid < 11) spd[tid] = spd_l[tid * NHEAD + hh];
    else if (tid < 19) et[tid - 11] = et_l[(tid - 11) * NHEAD + hh];
    if (tid < 64) { m_arr[tid] = -3.0e38f; l_arr[tid] = 0.f; }
    if (tid < 256) {
        int r = tid >> 2, sg = (tid & 3) * 8;
        *(uint4*)&qs[r][sg] = *(const uint4*)&qkvb[(size_t)(i0 + r) * 768 + hh * DH + sg];
    }

    int w = tid >> 6, lane = tid & 63;
    int r0 = (w >> 1) * 16;
    int c0 = (w & 1) * 32;
    int d0 = (w & 1) * 16;
    int m = lane & 15, quad = lane >> 4;
    int rr = tid >> 3, sub = tid & 7;
    const float scale = 0.17677669529663687f;

    __syncthreads();
    short8 aq = *(const short8*)&qs[r0 + m][quad * 8];
    f32x4 oacc = {0.f, 0.f, 0.f, 0.f};

    for (int j0 = 0; j0 < N_NODES; j0 += 64) {
        __syncthreads();   // protect ks/vs/S/P/pred reuse from previous iteration
        if (tid < 256) {
            int r = tid >> 2, sg = tid & 3;
            *(uint4*)&ks[r][sg * 8] =
                *(const uint4*)&qkvb[(size_t)(j0 + r) * 768 + 256 + hh * DH + sg * 8];
            *(uint4*)&bk[r][sg * 16] =
                *(const uint4*)&bucket[(size_t)(i0 + r) * N_NODES + j0 + sg * 16];
        } else {
            int t2 = tid - 256;
            int r = t2 >> 3, sg = (t2 & 7) * 8;
            *(uint4*)&vs[r][sg] = *(const uint4*)&vbt[(size_t)(hh * DH + r) * N_NODES + j0 + sg];
        }
        __syncthreads();
        // S = QK^T * scale + spd bias
        #pragma unroll
        for (int t = 0; t < 2; t++) {
            short8 bk8 = *(const short8*)&ks[c0 + t * 16 + m][quad * 8];
            f32x4 z = {0.f, 0.f, 0.f, 0.f};
            f32x4 sacc = __builtin_amdgcn_mfma_f32_16x16x32_bf16(aq, bk8, z, 0, 0, 0);
            #pragma unroll
            for (int reg = 0; reg < 4; reg++) {
                int rl = r0 + quad * 4 + reg, cl = c0 + t * 16 + m;
                S[rl][cl] = sacc[reg] * scale + spd[bk[rl][cl]];
            }
        }
        __syncthreads();
        // sparse edge bias into LDS tile
        {
            unsigned key0 = (unsigned)rb * 2048 + j0;
            unsigned start = offsets[key0], end = offsets[key0 + 64];
            for (unsigned i = start + tid; i < end; i += 512) {
                unsigned p = packed[i];
                int dl = (int)(p & 2047) - j0;
                int sl = (p >> 11) & 63;
                int ty = (p >> 17) & 7;
                atomicAdd(&S[sl][dl], et[ty]);
            }
        }
        __syncthreads();
        // row max partials (8 threads/row)
        float mx = -3.0e38f;
        #pragma unroll
        for (int i = 0; i < 8; i++) mx = fmaxf(mx, S[rr][sub * 8 + i]);
        pred[rr][sub] = mx;
        __syncthreads();
        if (sub == 0) {
            float t0 = pred[rr][0];
            #pragma unroll
            for (int i = 1; i < 8; i++) t0 = fmaxf(t0, pred[rr][i]);
            float mo = m_arr[rr];
            float mn = fmaxf(mo, t0);
            a_arr[rr] = __expf(mo - mn);
            m_arr[rr] = mn;
        }
        __syncthreads();
        // P = exp(S - m_new), partial sums
        float mn = m_arr[rr];
        float psum = 0.f;
        #pragma unroll
        for (int i = 0; i < 8; i++) {
            float pv = __expf(S[rr][sub * 8 + i] - mn);
            psum += pv;
            P[rr][sub * 8 + i] = f2bf(pv);
        }
        pred[rr][sub] = psum;
        __syncthreads();
        if (sub == 0) {
            float s0 = 0.f;
            #pragma unroll
            for (int i = 0; i < 8; i++) s0 += pred[rr][i];
            l_arr[rr] = l_arr[rr] * a_arr[rr] + s0;
        }
        // O = O*alpha + P@V  (reads P, vs, a_arr — all written before the last barrier)
        float av[4];
        #pragma unroll
        for (int reg = 0; reg < 4; reg++) av[reg] = a_arr[r0 + quad * 4 + reg];
        oacc[0] *= av[0]; oacc[1] *= av[1]; oacc[2] *= av[2]; oacc[3] *= av[3];
        #pragma unroll
        for (int kh = 0; kh < 2; kh++) {
            short8 pa = *(const short8*)&P[r0 + m][kh * 32 + quad * 8];
            short8 vb = *(const short8*)&vs[d0 + m][kh * 32 + quad * 8];
            oacc = __builtin_amdgcn_mfma_f32_16x16x32_bf16(pa, vb, oacc, 0, 0, 0);
        }
    }
    __syncthreads();
    #pragma unroll
    for (int reg = 0; reg < 4; reg++) {
        int rl = r0 + quad * 4 + reg;
        float val = oacc[reg] / l_arr[rl];
        aoutb[(size_t)(i0 + rl) * D_MODEL + hh * DH + d0 + m] = f2bf(val);
    }
}

extern "C" void kernel_launch(void* const* d_in, const int* in_sizes, int n_in,
                              void* d_out, int out_size, void* d_ws, size_t ws_size,
                              hipStream_t stream) {
    const float* x          = (const float*)d_in[0];
    const int*   edge_index = (const int*)d_in[1];
    const int*   edge_types = (const int*)d_in[2];
    const float* pos        = (const float*)d_in[3];
    const float* W_emb      = (const float*)d_in[4];
    const float* b_emb      = (const float*)d_in[5];
    const float* Wq         = (const float*)d_in[6];
    const float* Wk         = (const float*)d_in[7];
    const float* Wv         = (const float*)d_in[8];
    const float* Wo         = (const float*)d_in[9];
    const float* bq         = (const float*)d_in[10];
    const float* bk         = (const float*)d_in[11];
    const float* bv         = (const float*)d_in[12];
    const float* bo         = (const float*)d_in[13];
    const float* spd_table  = (const float*)d_in[14];
    const float* edge_table = (const float*)d_in[15];
    const float* din_emb    = (const float*)d_in[16];
    const float* dout_emb   = (const float*)d_in[17];
    const float* ln1_g      = (const float*)d_in[18];
    const float* ln1_b      = (const float*)d_in[19];
    const float* ln2_g      = (const float*)d_in[20];
    const float* ln2_b      = (const float*)d_in[21];
    const float* W1         = (const float*)d_in[22];
    const float* b1         = (const float*)d_in[23];
    const float* W2         = (const float*)d_in[24];
    const float* b2         = (const float*)d_in[25];
    const float* W_out      = (const float*)d_in[26];
    const float* b_out      = (const float*)d_in[27];
    float* out = (float*)d_out;

    char* base = (char*)d_ws;
    int* deg_out = (int*)base;                    base += (size_t)N_NODES * 4;
    int* deg_in  = (int*)base;                    base += (size_t)N_NODES * 4;
    float* h     = (float*)base;                  base += (size_t)N_NODES * D_MODEL * 4;
    unsigned short* hb   = (unsigned short*)base; base += (size_t)N_NODES * D_MODEL * 2;
    unsigned short* xb   = (unsigned short*)base; base += (size_t)N_NODES * D_MODEL * 2;
    unsigned short* xb0  = (unsigned short*)base; base += (size_t)N_NODES * D_FEAT * 2;
    unsigned short* qkvb = (unsigned short*)base; base += (size_t)N_NODES * 768 * 2;
    unsigned short* vbt  = (unsigned short*)base; base += (size_t)D_MODEL * N_NODES * 2;
    unsigned short* aoutb = (unsigned short*)base; base += (size_t)N_NODES * D_MODEL * 2;
    unsigned short* ffnb = (unsigned short*)base; base += (size_t)N_NODES * D_FF * 2;
    unsigned char* bucket = (unsigned char*)base; base += (size_t)N_NODES * N_NODES;
    unsigned short* qkvt = (unsigned short*)base; base += (size_t)NLAYER * 768 * D_MODEL * 2;
    unsigned short* wot  = (unsigned short*)base; base += (size_t)NLAYER * D_MODEL * D_MODEL * 2;
    unsigned short* w1t  = (unsigned short*)base; base += (size_t)NLAYER * D_MODEL * D_FF * 2;
    unsigned short* w2t  = (unsigned short*)base; base += (size_t)NLAYER * D_FF * D_MODEL * 2;
    unsigned short* wembt = (unsigned short*)base; base += (size_t)D_FEAT * D_MODEL * 2;
    unsigned short* woutt = (unsigned short*)base; base += (size_t)D_MODEL * D_OUT * 2;
    float* bqkv = (float*)base;                   base += (size_t)NLAYER * 768 * 4;
    unsigned* hist    = (unsigned*)base;          base += (size_t)65536 * 4;
    unsigned* offsets = (unsigned*)base;          base += (size_t)65537 * 4;
    unsigned* cursor  = (unsigned*)base;          base += (size_t)65536 * 4;
    unsigned* packed  = (unsigned*)base;          base += (size_t)NEDGE * 4;

    hipMemsetAsync(deg_out, 0, (size_t)N_NODES * 4 * 2, stream);
    hipMemsetAsync(hist, 0, (size_t)65536 * 4, stream);

    degree_kernel<<<NEDGE / 256, 256, 0, stream>>>(edge_index, deg_out, deg_in);

    // ---- one-time prep ----
    edge_hist_kernel<<<NEDGE / 256, 256, 0, stream>>>(edge_index, hist);
    edge_scan_kernel<<<1, 256, 0, stream>>>(hist, offsets, cursor);
    edge_scatter_kernel<<<NEDGE / 256, 256, 0, stream>>>(edge_index, edge_types, cursor, packed);
    wt_qkvo_kernel<<<dim3(8, 8, NLAYER * 4), 256, 0, stream>>>(Wq, Wk, Wv, Wo, qkvt, wot);
    wt_ffn1_kernel<<<dim3(D_FF / 32, D_MODEL / 32, NLAYER), 256, 0, stream>>>(W1, w1t);
    wt_ffn2_kernel<<<dim3(D_MODEL / 32, D_FF / 32, NLAYER), 256, 0, stream>>>(W2, w2t);
    wt_small_kernel<<<dim3(8, 8, 2), 256, 0, stream>>>(W_emb, W_out, wembt, woutt);
    bias_stack_kernel<<<NLAYER * 768 / 256, 256, 0, stream>>>(bq, bk, bv, bqkv);
    bucket_kernel<<<(size_t)N_NODES * N_NODES / 4 / 256, 256, 0, stream>>>(pos, bucket);
    cast_kernel<<<N_NODES * D_FEAT / 4 / 256, 256, 0, stream>>>(x, xb0);

    // embed
    gemm_mfma_kernel<0, false, false><<<dim3(D_MODEL / 64, N_NODES / 32), 256, 0, stream>>>(
        xb0, wembt, b_emb, h, nullptr, D_MODEL, D_FEAT);

    for (int l = 0; l < NLAYER; l++) {
        centrality_kernel<<<N_NODES * D_MODEL / 256, 256, 0, stream>>>(
            h, din_emb + (size_t)l * (MAXDEG + 1) * D_MODEL,
            dout_emb + (size_t)l * (MAXDEG + 1) * D_MODEL, deg_in, deg_out);

        layernorm_kernel<<<N_NODES, 256, 0, stream>>>(h, ln1_g + l * D_MODEL, ln1_b + l * D_MODEL, xb);

        gemm_mfma_kernel<0, false, true><<<dim3(768 / 64, N_NODES / 32), 256, 0, stream>>>(
            xb, qkvt + (size_t)l * 768 * D_MODEL, bqkv + l * 768, nullptr, qkvb, 768, D_MODEL);

        vbt_cast_kernel<<<dim3(D_MODEL / 32, N_NODES / 32), 256, 0, stream>>>(qkvb, vbt);

        flash_attn_kernel<<<dim3(N_NODES / 64, NHEAD), 512, 0, stream>>>(
            qkvb, vbt, bucket, spd_table + (size_t)l * 11 * NHEAD,
            edge_table + (size_t)l * 8 * NHEAD, offsets, packed, aoutb);

        gemm_mfma_kernel<0, true, false><<<dim3(D_MODEL / 64, N_NODES / 32), 256, 0, stream>>>(
            aoutb, wot + (size_t)l * D_MODEL * D_MODEL, bo + l * D_MODEL, h, nullptr, D_MODEL, D_MODEL);

        layernorm_kernel<<<N_NODES, 256, 0, stream>>>(h, ln2_g + l * D_MODEL, ln2_b + l * D_MODEL, xb);

        gemm_mfma_kernel<1, false, true><<<dim3(D_FF / 64, N_NODES / 32), 256, 0, stream>>>(
            xb, w1t + (size_t)l * D_MODEL * D_FF, b1 + l * D_FF, nullptr, ffnb, D_FF, D_MODEL);

        gemm_mfma_kernel<0, true, false><<<dim3(D_MODEL / 64, N_NODES / 32), 256, 0, stream>>>(
            ffnb, w2t + (size_t)l * D_FF * D_MODEL, b2 + l * D_MODEL, h, nullptr, D_MODEL, D_FF);
    }

    cast_kernel<<<N_NODES * D_MODEL / 4 / 256, 256, 0, stream>>>(h, hb);
    gemm_mfma_kernel<0, false, false><<<dim3(D_OUT / 64, N_NODES / 32), 256, 0, stream>>>(
        hb, woutt, b_out, out, nullptr, D_OUT, D_MODEL);
}

// Round 5
// 349.749 us; speedup vs baseline: 4.1115x; 1.2795x over previous
//
#include <hip/hip_runtime.h>
#include <math.h>

#define N_NODES 2048
#define D_MODEL 256
#define D_FEAT 128
#define NHEAD 8
#define DH 32
#define NLAYER 2
#define NEDGE 65536
#define D_FF 1024
#define D_OUT 128
#define MAXDEG 512
#define JSPLIT 4

typedef __attribute__((ext_vector_type(8))) short short8;
typedef __attribute__((ext_vector_type(4))) float f32x4;
typedef __attribute__((ext_vector_type(4))) unsigned short u16x4;

__device__ __forceinline__ unsigned short f2bf(float f) {
    unsigned u = __float_as_uint(f);
    unsigned r = (u + 0x7FFFu + ((u >> 16) & 1u)) >> 16;
    return (unsigned short)r;
}

// ---------------- degree count ----------------
__global__ void degree_kernel(const int* __restrict__ edge_index,
                              int* __restrict__ deg_out, int* __restrict__ deg_in) {
    int e = blockIdx.x * 256 + threadIdx.x;
    if (e < NEDGE) {
        atomicAdd(&deg_out[edge_index[e]], 1);
        atomicAdd(&deg_in[edge_index[NEDGE + e]], 1);
    }
}

// ---------------- centrality add ----------------
__global__ void centrality_kernel(float* __restrict__ h,
                                  const float* __restrict__ din_l,
                                  const float* __restrict__ dout_l,
                                  const int* __restrict__ deg_in,
                                  const int* __restrict__ deg_out) {
    int idx = blockIdx.x * 256 + threadIdx.x;
    int row = idx >> 8;
    int c = idx & 255;
    int di = min(deg_in[row], MAXDEG);
    int dn = min(deg_out[row], MAXDEG);
    h[idx] += din_l[di * D_MODEL + c] + dout_l[dn * D_MODEL + c];
}

// ---------------- layernorm: fp32 in -> bf16 out ----------------
__global__ void layernorm_kernel(const float* __restrict__ x,
                                 const float* __restrict__ g,
                                 const float* __restrict__ b,
                                 unsigned short* __restrict__ y) {
    int row = blockIdx.x;
    int tid = threadIdx.x;
    float v = x[row * D_MODEL + tid];
    __shared__ float red[256];
    red[tid] = v; __syncthreads();
    for (int s = 128; s > 0; s >>= 1) { if (tid < s) red[tid] += red[tid + s]; __syncthreads(); }
    float mu = red[0] * (1.0f / D_MODEL);
    __syncthreads();
    float d = v - mu;
    red[tid] = d * d; __syncthreads();
    for (int s = 128; s > 0; s >>= 1) { if (tid < s) red[tid] += red[tid + s]; __syncthreads(); }
    float rstd = rsqrtf(red[0] * (1.0f / D_MODEL) + 1e-5f);
    y[row * D_MODEL + tid] = f2bf(d * rstd * g[tid] + b[tid]);
}

// ---------------- generic fp32 -> bf16 cast ----------------
__global__ void cast_kernel(const float* __restrict__ src, unsigned short* __restrict__ dst) {
    int i = blockIdx.x * 256 + threadIdx.x;
    float4 p = *(const float4*)&src[(size_t)i * 4];
    u16x4 o;
    o[0] = f2bf(p.x); o[1] = f2bf(p.y); o[2] = f2bf(p.z); o[3] = f2bf(p.w);
    *(u16x4*)&dst[(size_t)i * 4] = o;
}

// ---------------- SPD bucket table: pos -> uint8 ----------------
__global__ void bucket_kernel(const float* __restrict__ pos, unsigned char* __restrict__ bucket) {
    int i = blockIdx.x * 256 + threadIdx.x;
    float4 p = *(const float4*)&pos[(size_t)i * 4];
    unsigned b0 = (unsigned)fminf(fmaxf(p.x * 10.f + 0.5f, 0.f), 10.f);
    unsigned b1 = (unsigned)fminf(fmaxf(p.y * 10.f + 0.5f, 0.f), 10.f);
    unsigned b2 = (unsigned)fminf(fmaxf(p.z * 10.f + 0.5f, 0.f), 10.f);
    unsigned b3 = (unsigned)fminf(fmaxf(p.w * 10.f + 0.5f, 0.f), 10.f);
    ((unsigned*)bucket)[i] = b0 | (b1 << 8) | (b2 << 16) | (b3 << 24);
}

// ---------------- edge CSR build: key = (src>>6)*2048 + dst ----------------
__global__ void edge_hist_kernel(const int* __restrict__ ei, unsigned* __restrict__ hist) {
    int e = blockIdx.x * 256 + threadIdx.x;
    if (e < NEDGE) {
        int key = (ei[e] >> 6) * 2048 + ei[NEDGE + e];
        atomicAdd(&hist[key], 1);
    }
}

__global__ void edge_scan1_kernel(const unsigned* __restrict__ hist,
                                  unsigned* __restrict__ offsets, unsigned* __restrict__ blocksum) {
    __shared__ unsigned tmp[256];
    int t = threadIdx.x;
    int g = blockIdx.x * 256 + t;
    unsigned v = hist[g];
    tmp[t] = v; __syncthreads();
    for (int off = 1; off < 256; off <<= 1) {
        unsigned u = (t >= off) ? tmp[t - off] : 0;
        __syncthreads();
        tmp[t] += u;
        __syncthreads();
    }
    offsets[g] = tmp[t] - v;      // exclusive within chunk
    if (t == 255) blocksum[blockIdx.x] = tmp[255];
}

__global__ void edge_scan2_kernel(unsigned* __restrict__ blocksum) {
    __shared__ unsigned tmp[256];
    int t = threadIdx.x;
    unsigned v = blocksum[t];
    tmp[t] = v; __syncthreads();
    for (int off = 1; off < 256; off <<= 1) {
        unsigned u = (t >= off) ? tmp[t - off] : 0;
        __syncthreads();
        tmp[t] += u;
        __syncthreads();
    }
    blocksum[t] = tmp[t] - v;     // exclusive
}

__global__ void edge_scan3_kernel(const unsigned* __restrict__ blocksum,
                                  unsigned* __restrict__ offsets, unsigned* __restrict__ cursor) {
    int g = blockIdx.x * 256 + threadIdx.x;
    unsigned o = offsets[g] + blocksum[blockIdx.x];
    offsets[g] = o; cursor[g] = o;
    if (g == 0) offsets[65536] = NEDGE;
}

__global__ void edge_scatter_kernel(const int* __restrict__ ei, const int* __restrict__ etypes,
                                    unsigned* __restrict__ cursor, unsigned* __restrict__ packed) {
    int e = blockIdx.x * 256 + threadIdx.x;
    if (e < NEDGE) {
        int src = ei[e], dst = ei[NEDGE + e];
        int key = (src >> 6) * 2048 + dst;
        unsigned pos = atomicAdd(&cursor[key], 1);
        packed[pos] = (unsigned)dst | ((unsigned)(src & 63) << 11) | ((unsigned)etypes[e] << 17);
    }
}

// ---------------- weight transpose+cast helper ----------------
__device__ __forceinline__ void wt_tile(const float* __restrict__ W, unsigned short* __restrict__ Wt,
                                        int K, int Nc, int n0, int k0, int tid,
                                        unsigned short (*tile)[33]) {
    int r = tid >> 3, cg = (tid & 7) * 4;
    float4 w4 = *(const float4*)&W[(size_t)(k0 + r) * Nc + n0 + cg];
    tile[r][cg + 0] = f2bf(w4.x); tile[r][cg + 1] = f2bf(w4.y);
    tile[r][cg + 2] = f2bf(w4.z); tile[r][cg + 3] = f2bf(w4.w);
    __syncthreads();
    int c = tid >> 3, rg = (tid & 7) * 4;
    u16x4 o;
    #pragma unroll
    for (int j = 0; j < 4; j++) o[j] = tile[rg + j][c];
    *(u16x4*)&Wt[(size_t)(n0 + c) * K + k0 + rg] = o;
}

__global__ void wt_qkvo_kernel(const float* __restrict__ Wq, const float* __restrict__ Wk,
                               const float* __restrict__ Wv, const float* __restrict__ Wo,
                               unsigned short* __restrict__ qkvt, unsigned short* __restrict__ wot) {
    __shared__ unsigned short tile[32][33];
    int z = blockIdx.z, l = z >> 2, which = z & 3;
    const float* W = (which == 0 ? Wq : which == 1 ? Wk : which == 2 ? Wv : Wo) + (size_t)l * 65536;
    unsigned short* dst = (which < 3) ? qkvt + (size_t)l * 196608 + which * 65536
                                      : wot + (size_t)l * 65536;
    wt_tile(W, dst, 256, 256, blockIdx.x * 32, blockIdx.y * 32, threadIdx.x, tile);
}

__global__ void wt_ffn1_kernel(const float* __restrict__ W1, unsigned short* __restrict__ w1t) {
    __shared__ unsigned short tile[32][33];
    int l = blockIdx.z;
    wt_tile(W1 + (size_t)l * D_MODEL * D_FF, w1t + (size_t)l * D_MODEL * D_FF,
            D_MODEL, D_FF, blockIdx.x * 32, blockIdx.y * 32, threadIdx.x, tile);
}

__global__ void wt_ffn2_kernel(const float* __restrict__ W2, unsigned short* __restrict__ w2t) {
    __shared__ unsigned short tile[32][33];
    int l = blockIdx.z;
    wt_tile(W2 + (size_t)l * D_FF * D_MODEL, w2t + (size_t)l * D_FF * D_MODEL,
            D_FF, D_MODEL, blockIdx.x * 32, blockIdx.y * 32, threadIdx.x, tile);
}

__global__ void wt_small_kernel(const float* __restrict__ W_emb, const float* __restrict__ W_out,
                                unsigned short* __restrict__ wembt, unsigned short* __restrict__ woutt) {
    __shared__ unsigned short tile[32][33];
    if (blockIdx.z == 0) {
        if (blockIdx.y >= 4) return;
        wt_tile(W_emb, wembt, D_FEAT, D_MODEL, blockIdx.x * 32, blockIdx.y * 32, threadIdx.x, tile);
    } else {
        if (blockIdx.x >= 4) return;
        wt_tile(W_out, woutt, D_MODEL, D_OUT, blockIdx.x * 32, blockIdx.y * 32, threadIdx.x, tile);
    }
}

__global__ void bias_stack_kernel(const float* __restrict__ bq, const float* __restrict__ bk,
                                  const float* __restrict__ bv, float* __restrict__ bqkv) {
    int i = blockIdx.x * 256 + threadIdx.x;
    int l = i / 768, j = i % 768;
    const float* src = j < 256 ? bq : j < 512 ? bk : bv;
    bqkv[i] = src[l * 256 + (j & 255)];
}

// ---------------- bf16 MFMA GEMM, 32x64 tile ----------------
template <int ACT, bool RESID, bool OUTBF16>
__global__ void gemm_mfma_kernel(const unsigned short* __restrict__ A,
                                 const unsigned short* __restrict__ Wt,
                                 const float* __restrict__ bias,
                                 float* __restrict__ C, unsigned short* __restrict__ Cb,
                                 int Nc, int K) {
    __shared__ __align__(16) unsigned short As[32][72];
    __shared__ __align__(16) unsigned short Bs[64][72];
    int tid = threadIdx.x;
    int m0 = blockIdx.y * 32, n0 = blockIdx.x * 64;
    int w = tid >> 6, lane = tid & 63;
    int rg = (w & 1) * 16, cg = (w >> 1) * 32;
    int m = lane & 15, quad = lane >> 4;
    f32x4 acc[2] = {{0.f, 0.f, 0.f, 0.f}, {0.f, 0.f, 0.f, 0.f}};
    int ar = tid >> 3, ac = (tid & 7) * 8;
    for (int k0 = 0; k0 < K; k0 += 64) {
        *(uint4*)&As[ar][ac] = *(const uint4*)&A[(size_t)(m0 + ar) * K + k0 + ac];
        *(uint4*)&Bs[ar][ac] = *(const uint4*)&Wt[(size_t)(n0 + ar) * K + k0 + ac];
        *(uint4*)&Bs[ar + 32][ac] = *(const uint4*)&Wt[(size_t)(n0 + 32 + ar) * K + k0 + ac];
        __syncthreads();
        #pragma unroll
        for (int ks = 0; ks < 2; ks++) {
            short8 a = *(const short8*)&As[rg + m][ks * 32 + quad * 8];
            #pragma unroll
            for (int t = 0; t < 2; t++) {
                short8 b = *(const short8*)&Bs[cg + t * 16 + m][ks * 32 + quad * 8];
                acc[t] = __builtin_amdgcn_mfma_f32_16x16x32_bf16(a, b, acc[t], 0, 0, 0);
            }
        }
        __syncthreads();
    }
    #pragma unroll
    for (int t = 0; t < 2; t++) {
        #pragma unroll
        for (int reg = 0; reg < 4; reg++) {
            int row = m0 + rg + quad * 4 + reg;
            int col = n0 + cg + t * 16 + m;
            float val = acc[t][reg] + bias[col];
            if (ACT == 1) val = val * 0.5f * (1.0f + erff(val * 0.7071067811865476f));
            size_t idx = (size_t)row * Nc + col;
            if (RESID) val += C[idx];
            if (OUTBF16) Cb[idx] = f2bf(val);
            else C[idx] = val;
        }
    }
}

// ---------------- bf16 MFMA GEMM, 64x64 tile (qkv / ffn1) ----------------
template <int ACT, bool OUTBF16>
__global__ void gemm64_kernel(const unsigned short* __restrict__ A,
                              const unsigned short* __restrict__ Wt,
                              const float* __restrict__ bias,
                              float* __restrict__ C, unsigned short* __restrict__ Cb,
                              int Nc, int K) {
    __shared__ __align__(16) unsigned short As[64][72];
    __shared__ __align__(16) unsigned short Bs[64][72];
    int tid = threadIdx.x;
    int m0 = blockIdx.y * 64, n0 = blockIdx.x * 64;
    int w = tid >> 6, lane = tid & 63;
    int wr = (w & 1) * 32, wc = (w >> 1) * 32;
    int m = lane & 15, quad = lane >> 4;
    f32x4 acc[2][2] = {{{0.f,0.f,0.f,0.f},{0.f,0.f,0.f,0.f}},{{0.f,0.f,0.f,0.f},{0.f,0.f,0.f,0.f}}};
    int sr = tid >> 2, sg = (tid & 3) * 16;
    for (int k0 = 0; k0 < K; k0 += 64) {
        *(uint4*)&As[sr][sg] = *(const uint4*)&A[(size_t)(m0 + sr) * K + k0 + sg];
        *(uint4*)&As[sr][sg + 8] = *(const uint4*)&A[(size_t)(m0 + sr) * K + k0 + sg + 8];
        *(uint4*)&Bs[sr][sg] = *(const uint4*)&Wt[(size_t)(n0 + sr) * K + k0 + sg];
        *(uint4*)&Bs[sr][sg + 8] = *(const uint4*)&Wt[(size_t)(n0 + sr) * K + k0 + sg + 8];
        __syncthreads();
        #pragma unroll
        for (int kh = 0; kh < 2; kh++) {
            short8 a0 = *(const short8*)&As[wr + m][kh * 32 + quad * 8];
            short8 a1 = *(const short8*)&As[wr + 16 + m][kh * 32 + quad * 8];
            short8 b0 = *(const short8*)&Bs[wc + m][kh * 32 + quad * 8];
            short8 b1 = *(const short8*)&Bs[wc + 16 + m][kh * 32 + quad * 8];
            acc[0][0] = __builtin_amdgcn_mfma_f32_16x16x32_bf16(a0, b0, acc[0][0], 0, 0, 0);
            acc[0][1] = __builtin_amdgcn_mfma_f32_16x16x32_bf16(a0, b1, acc[0][1], 0, 0, 0);
            acc[1][0] = __builtin_amdgcn_mfma_f32_16x16x32_bf16(a1, b0, acc[1][0], 0, 0, 0);
            acc[1][1] = __builtin_amdgcn_mfma_f32_16x16x32_bf16(a1, b1, acc[1][1], 0, 0, 0);
        }
        __syncthreads();
    }
    #pragma unroll
    for (int mt = 0; mt < 2; mt++) {
        #pragma unroll
        for (int nt = 0; nt < 2; nt++) {
            #pragma unroll
            for (int reg = 0; reg < 4; reg++) {
                int row = m0 + wr + mt * 16 + quad * 4 + reg;
                int col = n0 + wc + nt * 16 + m;
                float val = acc[mt][nt][reg] + bias[col];
                if (ACT == 1) val = val * 0.5f * (1.0f + erff(val * 0.7071067811865476f));
                size_t idx = (size_t)row * Nc + col;
                if (OUTBF16) Cb[idx] = f2bf(val);
                else C[idx] = val;
            }
        }
    }
}

// ---------------- transpose v slice of qkvb -> vbt (bf16 [DH*H][N]) ----------------
__global__ void vbt_cast_kernel(const unsigned short* __restrict__ qkvb,
                                unsigned short* __restrict__ vbt) {
    __shared__ unsigned short tile[32][33];
    int c0 = blockIdx.x * 32, r0 = blockIdx.y * 32;
    int tid = threadIdx.x;
    int r = tid >> 3, cg = (tid & 7) * 4;
    u16x4 v4 = *(const u16x4*)&qkvb[(size_t)(r0 + r) * 768 + 512 + c0 + cg];
    tile[r][cg + 0] = v4[0]; tile[r][cg + 1] = v4[1];
    tile[r][cg + 2] = v4[2]; tile[r][cg + 3] = v4[3];
    __syncthreads();
    int c = tid >> 3, rg = (tid & 7) * 4;
    u16x4 o;
    #pragma unroll
    for (int j = 0; j < 4; j++) o[j] = tile[rg + j][c];
    *(u16x4*)&vbt[(size_t)(c0 + c) * N_NODES + r0 + rg] = o;
}

// ---------------- flash attention, wave-owned rows + j-split ----------------
// grid (N/64, H, JSPLIT), block 256 = 4 waves. Wave w owns rows w*16..+16.
__global__ __launch_bounds__(256)
void flash_attn_kernel(const unsigned short* __restrict__ qkvb,
                       const unsigned short* __restrict__ vbt,
                       const unsigned char* __restrict__ bucket,
                       const float* __restrict__ spd_l,
                       const float* __restrict__ et_l,
                       const unsigned* __restrict__ offsets,
                       const unsigned* __restrict__ packed,
                       float* __restrict__ part_O,
                       float* __restrict__ m_part, float* __restrict__ l_part) {
    __shared__ __align__(16) unsigned short ks[64][40];
    __shared__ __align__(16) unsigned short vs[32][72];
    __shared__ __align__(16) float sbias[64][68];
    __shared__ __align__(16) unsigned short P[4][16][72];
    __shared__ float spd[11], et[8];

    int tid = threadIdx.x;
    int rb = blockIdx.x;
    int i0 = rb * 64;
    int hh = blockIdx.y;
    int js = blockIdx.z;
    if (tid < 11) spd[tid] = spd_l[tid * NHEAD + hh];
    else if (tid < 19) et[tid - 11] = et_l[(tid - 11) * NHEAD + hh];

    int w = tid >> 6, lane = tid & 63;
    int m = lane & 15, quad = lane >> 4;
    int r0 = w * 16;
    // Q fragment (A-layout), lives in registers for the whole kernel
    short8 aq = *(const short8*)&qkvb[(size_t)(i0 + r0 + m) * 768 + hh * DH + quad * 8];
    float m_st[4], l_st[4];
    #pragma unroll
    for (int r = 0; r < 4; r++) { m_st[r] = -3.0e38f; l_st[r] = 0.f; }
    f32x4 oacc[2] = {{0.f, 0.f, 0.f, 0.f}, {0.f, 0.f, 0.f, 0.f}};
    const float scale = 0.17677669529663687f;

    for (int jt = 0; jt < N_NODES / JSPLIT / 64; jt++) {
        int j0 = js * (N_NODES / JSPLIT) + jt * 64;
        __syncthreads();                              // staging buffers free
        { int r = tid >> 2, kg = (tid & 3) * 8;
          *(uint4*)&ks[r][kg] = *(const uint4*)&qkvb[(size_t)(j0 + r) * 768 + 256 + hh * DH + kg]; }
        { int r = tid >> 3, cg = (tid & 7) * 8;
          *(uint4*)&vs[r][cg] = *(const uint4*)&vbt[(size_t)(hh * DH + r) * N_NODES + j0 + cg]; }
        { int r = tid >> 2, cg = (tid & 3) * 16;
          uint4 b16 = *(const uint4*)&bucket[(size_t)(i0 + r) * N_NODES + j0 + cg];
          const unsigned char* bb = (const unsigned char*)&b16;
          #pragma unroll
          for (int i = 0; i < 16; i++) sbias[r][cg + i] = spd[bb[i]];
        }
        __syncthreads();                              // sbias initialized
        { unsigned key0 = (unsigned)rb * 2048 + j0;
          unsigned start = offsets[key0], end = offsets[key0 + 64];
          for (unsigned i = start + tid; i < end; i += 256) {
              unsigned p = packed[i];
              atomicAdd(&sbias[(p >> 11) & 63][(p & 2047) - j0], et[(p >> 17) & 7]);
          }
        }
        __syncthreads();                              // edge bias applied
        // S tile in registers (C-layout)
        float sv[4][4];
        #pragma unroll
        for (int t = 0; t < 4; t++) {
            short8 bk8 = *(const short8*)&ks[t * 16 + m][quad * 8];
            f32x4 z = {0.f, 0.f, 0.f, 0.f};
            f32x4 sacc = __builtin_amdgcn_mfma_f32_16x16x32_bf16(aq, bk8, z, 0, 0, 0);
            #pragma unroll
            for (int r = 0; r < 4; r++)
                sv[t][r] = sacc[r] * scale + sbias[r0 + quad * 4 + r][t * 16 + m];
        }
        // per-row online softmax via 16-lane shuffles (rows owned by quad groups)
        float alpha[4];
        #pragma unroll
        for (int r = 0; r < 4; r++) {
            float mx = fmaxf(fmaxf(sv[0][r], sv[1][r]), fmaxf(sv[2][r], sv[3][r]));
            #pragma unroll
            for (int off = 1; off < 16; off <<= 1) mx = fmaxf(mx, __shfl_xor(mx, off, 64));
            float mn = fmaxf(m_st[r], mx);
            alpha[r] = __expf(m_st[r] - mn);
            m_st[r] = mn;
            float ps = 0.f;
            #pragma unroll
            for (int t = 0; t < 4; t++) { float pv = __expf(sv[t][r] - mn); sv[t][r] = pv; ps += pv; }
            #pragma unroll
            for (int off = 1; off < 16; off <<= 1) ps += __shfl_xor(ps, off, 64);
            l_st[r] = l_st[r] * alpha[r] + ps;
        }
        // P -> per-wave LDS region (C-layout write, A-layout read; intra-wave only)
        #pragma unroll
        for (int t = 0; t < 4; t++)
            #pragma unroll
            for (int r = 0; r < 4; r++)
                P[w][quad * 4 + r][t * 16 + m] = f2bf(sv[t][r]);
        #pragma unroll
        for (int r = 0; r < 4; r++) { oacc[0][r] *= alpha[r]; oacc[1][r] *= alpha[r]; }
        __builtin_amdgcn_s_waitcnt(0xC07F);           // lgkmcnt(0): P writes visible to own wave
        #pragma unroll
        for (int kh = 0; kh < 2; kh++) {
            short8 pa = *(const short8*)&P[w][m][kh * 32 + quad * 8];
            #pragma unroll
            for (int t = 0; t < 2; t++) {
                short8 vb = *(const short8*)&vs[t * 16 + m][kh * 32 + quad * 8];
                oacc[t] = __builtin_amdgcn_mfma_f32_16x16x32_bf16(pa, vb, oacc[t], 0, 0, 0);
            }
        }
    }
    // write partials (unnormalized O, local m, local l)
    #pragma unroll
    for (int t = 0; t < 2; t++)
        #pragma unroll
        for (int r = 0; r < 4; r++)
            part_O[((size_t)js * N_NODES + i0 + r0 + quad * 4 + r) * D_MODEL + hh * DH + t * 16 + m] =
                oacc[t][r];
    if (m == 0) {
        #pragma unroll
        for (int r = 0; r < 4; r++) {
            int row = i0 + r0 + quad * 4 + r;
            m_part[((size_t)js * NHEAD + hh) * N_NODES + row] = m_st[r];
            l_part[((size_t)js * NHEAD + hh) * N_NODES + row] = l_st[r];
        }
    }
}

// ---------------- merge j-split partials -> bf16 attn out ----------------
__global__ void flash_merge_kernel(const float* __restrict__ part_O,
                                   const float* __restrict__ m_part,
                                   const float* __restrict__ l_part,
                                   unsigned short* __restrict__ aoutb) {
    int e = blockIdx.x * 256 + threadIdx.x;           // N*D elements
    int row = e >> 8, col = e & 255, h = col >> 5;
    float mv[JSPLIT];
    float mg = -3.0e38f;
    #pragma unroll
    for (int js = 0; js < JSPLIT; js++) {
        mv[js] = m_part[((size_t)js * NHEAD + h) * N_NODES + row];
        mg = fmaxf(mg, mv[js]);
    }
    float o = 0.f, l = 0.f;
    #pragma unroll
    for (int js = 0; js < JSPLIT; js++) {
        float sc = __expf(mv[js] - mg);
        o += sc * part_O[(size_t)js * N_NODES * D_MODEL + e];
        l += sc * l_part[((size_t)js * NHEAD + h) * N_NODES + row];
    }
    aoutb[e] = f2bf(o / l);
}

extern "C" void kernel_launch(void* const* d_in, const int* in_sizes, int n_in,
                              void* d_out, int out_size, void* d_ws, size_t ws_size,
                              hipStream_t stream) {
    const float* x          = (const float*)d_in[0];
    const int*   edge_index = (const int*)d_in[1];
    const int*   edge_types = (const int*)d_in[2];
    const float* pos        = (const float*)d_in[3];
    const float* W_emb      = (const float*)d_in[4];
    const float* b_emb      = (const float*)d_in[5];
    const float* Wq         = (const float*)d_in[6];
    const float* Wk         = (const float*)d_in[7];
    const float* Wv         = (const float*)d_in[8];
    const float* Wo         = (const float*)d_in[9];
    const float* bq         = (const float*)d_in[10];
    const float* bk         = (const float*)d_in[11];
    const float* bv         = (const float*)d_in[12];
    const float* bo         = (const float*)d_in[13];
    const float* spd_table  = (const float*)d_in[14];
    const float* edge_table = (const float*)d_in[15];
    const float* din_emb    = (const float*)d_in[16];
    const float* dout_emb   = (const float*)d_in[17];
    const float* ln1_g      = (const float*)d_in[18];
    const float* ln1_b      = (const float*)d_in[19];
    const float* ln2_g      = (const float*)d_in[20];
    const float* ln2_b      = (const float*)d_in[21];
    const float* W1         = (const float*)d_in[22];
    const float* b1         = (const float*)d_in[23];
    const float* W2         = (const float*)d_in[24];
    const float* b2         = (const float*)d_in[25];
    const float* W_out      = (const float*)d_in[26];
    const float* b_out      = (const float*)d_in[27];
    float* out = (float*)d_out;

    char* base = (char*)d_ws;
    int* deg_out = (int*)base;                    base += (size_t)N_NODES * 4;
    int* deg_in  = (int*)base;                    base += (size_t)N_NODES * 4;
    float* h     = (float*)base;                  base += (size_t)N_NODES * D_MODEL * 4;
    unsigned short* hb   = (unsigned short*)base; base += (size_t)N_NODES * D_MODEL * 2;
    unsigned short* xb   = (unsigned short*)base; base += (size_t)N_NODES * D_MODEL * 2;
    unsigned short* xb0  = (unsigned short*)base; base += (size_t)N_NODES * D_FEAT * 2;
    unsigned short* qkvb = (unsigned short*)base; base += (size_t)N_NODES * 768 * 2;
    unsigned short* vbt  = (unsigned short*)base; base += (size_t)D_MODEL * N_NODES * 2;
    unsigned short* aoutb = (unsigned short*)base; base += (size_t)N_NODES * D_MODEL * 2;
    unsigned short* ffnb = (unsigned short*)base; base += (size_t)N_NODES * D_FF * 2;
    unsigned char* bucket = (unsigned char*)base; base += (size_t)N_NODES * N_NODES;
    unsigned short* qkvt = (unsigned short*)base; base += (size_t)NLAYER * 768 * D_MODEL * 2;
    unsigned short* wot  = (unsigned short*)base; base += (size_t)NLAYER * D_MODEL * D_MODEL * 2;
    unsigned short* w1t  = (unsigned short*)base; base += (size_t)NLAYER * D_MODEL * D_FF * 2;
    unsigned short* w2t  = (unsigned short*)base; base += (size_t)NLAYER * D_FF * D_MODEL * 2;
    unsigned short* wembt = (unsigned short*)base; base += (size_t)D_FEAT * D_MODEL * 2;
    unsigned short* woutt = (unsigned short*)base; base += (size_t)D_MODEL * D_OUT * 2;
    float* bqkv = (float*)base;                   base += (size_t)NLAYER * 768 * 4;
    unsigned* hist    = (unsigned*)base;          base += (size_t)65536 * 4;
    unsigned* offsets = (unsigned*)base;          base += (size_t)65537 * 4;
    unsigned* cursor  = (unsigned*)base;          base += (size_t)65536 * 4;
    unsigned* blocksum = (unsigned*)base;         base += (size_t)256 * 4;
    unsigned* packed  = (unsigned*)base;          base += (size_t)NEDGE * 4;
    float* part_O = (float*)base;                 base += (size_t)JSPLIT * N_NODES * D_MODEL * 4;
    float* m_part = (float*)base;                 base += (size_t)JSPLIT * NHEAD * N_NODES * 4;
    float* l_part = (float*)base;                 base += (size_t)JSPLIT * NHEAD * N_NODES * 4;

    hipMemsetAsync(deg_out, 0, (size_t)N_NODES * 4 * 2, stream);
    hipMemsetAsync(hist, 0, (size_t)65536 * 4, stream);

    degree_kernel<<<NEDGE / 256, 256, 0, stream>>>(edge_index, deg_out, deg_in);

    // ---- one-time prep ----
    edge_hist_kernel<<<NEDGE / 256, 256, 0, stream>>>(edge_index, hist);
    edge_scan1_kernel<<<256, 256, 0, stream>>>(hist, offsets, blocksum);
    edge_scan2_kernel<<<1, 256, 0, stream>>>(blocksum);
    edge_scan3_kernel<<<256, 256, 0, stream>>>(blocksum, offsets, cursor);
    edge_scatter_kernel<<<NEDGE / 256, 256, 0, stream>>>(edge_index, edge_types, cursor, packed);
    wt_qkvo_kernel<<<dim3(8, 8, NLAYER * 4), 256, 0, stream>>>(Wq, Wk, Wv, Wo, qkvt, wot);
    wt_ffn1_kernel<<<dim3(D_FF / 32, D_MODEL / 32, NLAYER), 256, 0, stream>>>(W1, w1t);
    wt_ffn2_kernel<<<dim3(D_MODEL / 32, D_FF / 32, NLAYER), 256, 0, stream>>>(W2, w2t);
    wt_small_kernel<<<dim3(8, 8, 2), 256, 0, stream>>>(W_emb, W_out, wembt, woutt);
    bias_stack_kernel<<<NLAYER * 768 / 256, 256, 0, stream>>>(bq, bk, bv, bqkv);
    bucket_kernel<<<(size_t)N_NODES * N_NODES / 4 / 256, 256, 0, stream>>>(pos, bucket);
    cast_kernel<<<N_NODES * D_FEAT / 4 / 256, 256, 0, stream>>>(x, xb0);

    // embed
    gemm_mfma_kernel<0, false, false><<<dim3(D_MODEL / 64, N_NODES / 32), 256, 0, stream>>>(
        xb0, wembt, b_emb, h, nullptr, D_MODEL, D_FEAT);

    for (int l = 0; l < NLAYER; l++) {
        centrality_kernel<<<N_NODES * D_MODEL / 256, 256, 0, stream>>>(
            h, din_emb + (size_t)l * (MAXDEG + 1) * D_MODEL,
            dout_emb + (size_t)l * (MAXDEG + 1) * D_MODEL, deg_in, deg_out);

        layernorm_kernel<<<N_NODES, 256, 0, stream>>>(h, ln1_g + l * D_MODEL, ln1_b + l * D_MODEL, xb);

        gemm64_kernel<0, true><<<dim3(768 / 64, N_NODES / 64), 256, 0, stream>>>(
            xb, qkvt + (size_t)l * 768 * D_MODEL, bqkv + l * 768, nullptr, qkvb, 768, D_MODEL);

        vbt_cast_kernel<<<dim3(D_MODEL / 32, N_NODES / 32), 256, 0, stream>>>(qkvb, vbt);

        flash_attn_kernel<<<dim3(N_NODES / 64, NHEAD, JSPLIT), 256, 0, stream>>>(
            qkvb, vbt, bucket, spd_table + (size_t)l * 11 * NHEAD,
            edge_table + (size_t)l * 8 * NHEAD, offsets, packed, part_O, m_part, l_part);

        flash_merge_kernel<<<N_NODES * D_MODEL / 256, 256, 0, stream>>>(part_O, m_part, l_part, aoutb);

        gemm_mfma_kernel<0, true, false><<<dim3(D_MODEL / 64, N_NODES / 32), 256, 0, stream>>>(
            aoutb, wot + (size_t)l * D_MODEL * D_MODEL, bo + l * D_MODEL, h, nullptr, D_MODEL, D_MODEL);

        layernorm_kernel<<<N_NODES, 256, 0, stream>>>(h, ln2_g + l * D_MODEL, ln2_b + l * D_MODEL, xb);

        gemm64_kernel<1, true><<<dim3(D_FF / 64, N_NODES / 64), 256, 0, stream>>>(
            xb, w1t + (size_t)l * D_MODEL * D_FF, b1 + l * D_FF, nullptr, ffnb, D_FF, D_MODEL);

        gemm_mfma_kernel<0, true, false><<<dim3(D_MODEL / 64, N_NODES / 32), 256, 0, stream>>>(
            ffnb, w2t + (size_t)l * D_FF * D_MODEL, b2 + l * D_MODEL, h, nullptr, D_MODEL, D_FF);
    }

    cast_kernel<<<N_NODES * D_MODEL / 4 / 256, 256, 0, stream>>>(h, hb);
    gemm_mfma_kernel<0, false, false><<<dim3(D_OUT / 64, N_NODES / 32), 256, 0, stream>>>(
        hb, woutt, b_out, out, nullptr, D_OUT, D_MODEL);
}

// Round 6
// 314.380 us; speedup vs baseline: 4.5740x; 1.1125x over previous
//
#include <hip/hip_runtime.h>
#include <math.h>

#define N_NODES 2048
#define D_MODEL 256
#define D_FEAT 128
#define NHEAD 8
#define DH 32
#define NLAYER 2
#define NEDGE 65536
#define D_FF 1024
#define D_OUT 128
#define MAXDEG 512
#define JSPLIT 4

typedef __attribute__((ext_vector_type(8))) short short8;
typedef __attribute__((ext_vector_type(4))) float f32x4;
typedef __attribute__((ext_vector_type(4))) unsigned short u16x4;

__device__ __forceinline__ unsigned short f2bf(float f) {
    unsigned u = __float_as_uint(f);
    unsigned r = (u + 0x7FFFu + ((u >> 16) & 1u)) >> 16;
    return (unsigned short)r;
}

// DPP row-rotate (16-lane row) on the VALU pipe — replaces __shfl_xor (LDS pipe)
template <int CTRL>
__device__ __forceinline__ float dpp_ror(float x) {
    return __int_as_float(__builtin_amdgcn_update_dpp(0, __float_as_int(x), CTRL, 0xf, 0xf, false));
}

// ---------------- degree + edge histogram (fused) ----------------
__global__ void degree_hist_kernel(const int* __restrict__ ei,
                                   int* __restrict__ deg_out, int* __restrict__ deg_in,
                                   unsigned* __restrict__ hist) {
    int e = blockIdx.x * 256 + threadIdx.x;
    if (e < NEDGE) {
        int src = ei[e], dst = ei[NEDGE + e];
        atomicAdd(&deg_out[src], 1);
        atomicAdd(&deg_in[dst], 1);
        atomicAdd(&hist[(src >> 6) * 2048 + dst], 1);
    }
}

__global__ void edge_scan1_kernel(const unsigned* __restrict__ hist,
                                  unsigned* __restrict__ offsets, unsigned* __restrict__ blocksum) {
    __shared__ unsigned tmp[256];
    int t = threadIdx.x;
    int g = blockIdx.x * 256 + t;
    unsigned v = hist[g];
    tmp[t] = v; __syncthreads();
    for (int off = 1; off < 256; off <<= 1) {
        unsigned u = (t >= off) ? tmp[t - off] : 0;
        __syncthreads();
        tmp[t] += u;
        __syncthreads();
    }
    offsets[g] = tmp[t] - v;
    if (t == 255) blocksum[blockIdx.x] = tmp[255];
}

__global__ void edge_scan2_kernel(unsigned* __restrict__ blocksum) {
    __shared__ unsigned tmp[256];
    int t = threadIdx.x;
    unsigned v = blocksum[t];
    tmp[t] = v; __syncthreads();
    for (int off = 1; off < 256; off <<= 1) {
        unsigned u = (t >= off) ? tmp[t - off] : 0;
        __syncthreads();
        tmp[t] += u;
        __syncthreads();
    }
    blocksum[t] = tmp[t] - v;
}

__global__ void edge_scan3_kernel(const unsigned* __restrict__ blocksum,
                                  unsigned* __restrict__ offsets, unsigned* __restrict__ cursor) {
    int g = blockIdx.x * 256 + threadIdx.x;
    unsigned o = offsets[g] + blocksum[blockIdx.x];
    offsets[g] = o; cursor[g] = o;
    if (g == 0) offsets[65536] = NEDGE;
}

__global__ void edge_scatter_kernel(const int* __restrict__ ei, const int* __restrict__ etypes,
                                    unsigned* __restrict__ cursor, unsigned* __restrict__ packed) {
    int e = blockIdx.x * 256 + threadIdx.x;
    if (e < NEDGE) {
        int src = ei[e], dst = ei[NEDGE + e];
        int key = (src >> 6) * 2048 + dst;
        unsigned pos = atomicAdd(&cursor[key], 1);
        packed[pos] = (unsigned)dst | ((unsigned)(src & 63) << 11) | ((unsigned)etypes[e] << 17);
    }
}

// ---------------- SPD bucket table: pos -> uint8 ----------------
__global__ void bucket_kernel(const float* __restrict__ pos, unsigned char* __restrict__ bucket) {
    int i = blockIdx.x * 256 + threadIdx.x;
    float4 p = *(const float4*)&pos[(size_t)i * 4];
    unsigned b0 = (unsigned)fminf(fmaxf(p.x * 10.f + 0.5f, 0.f), 10.f);
    unsigned b1 = (unsigned)fminf(fmaxf(p.y * 10.f + 0.5f, 0.f), 10.f);
    unsigned b2 = (unsigned)fminf(fmaxf(p.z * 10.f + 0.5f, 0.f), 10.f);
    unsigned b3 = (unsigned)fminf(fmaxf(p.w * 10.f + 0.5f, 0.f), 10.f);
    ((unsigned*)bucket)[i] = b0 | (b1 << 8) | (b2 << 16) | (b3 << 24);
}

// ---------------- fused centrality + layernorm1 ----------------
__global__ void centrality_ln_kernel(float* __restrict__ h,
                                     const float* __restrict__ din_l,
                                     const float* __restrict__ dout_l,
                                     const int* __restrict__ deg_in,
                                     const int* __restrict__ deg_out,
                                     const float* __restrict__ g,
                                     const float* __restrict__ b,
                                     unsigned short* __restrict__ y) {
    int row = blockIdx.x;
    int tid = threadIdx.x;
    int di = min(deg_in[row], MAXDEG);
    int dn = min(deg_out[row], MAXDEG);
    float v = h[row * D_MODEL + tid] + din_l[di * D_MODEL + tid] + dout_l[dn * D_MODEL + tid];
    h[row * D_MODEL + tid] = v;
    __shared__ float red[256];
    red[tid] = v; __syncthreads();
    for (int s = 128; s > 0; s >>= 1) { if (tid < s) red[tid] += red[tid + s]; __syncthreads(); }
    float mu = red[0] * (1.0f / D_MODEL);
    __syncthreads();
    float d = v - mu;
    red[tid] = d * d; __syncthreads();
    for (int s = 128; s > 0; s >>= 1) { if (tid < s) red[tid] += red[tid + s]; __syncthreads(); }
    float rstd = rsqrtf(red[0] * (1.0f / D_MODEL) + 1e-5f);
    y[row * D_MODEL + tid] = f2bf(d * rstd * g[tid] + b[tid]);
}

// ---------------- layernorm2: fp32 in -> bf16 out ----------------
__global__ void layernorm_kernel(const float* __restrict__ x,
                                 const float* __restrict__ g,
                                 const float* __restrict__ b,
                                 unsigned short* __restrict__ y) {
    int row = blockIdx.x;
    int tid = threadIdx.x;
    float v = x[row * D_MODEL + tid];
    __shared__ float red[256];
    red[tid] = v; __syncthreads();
    for (int s = 128; s > 0; s >>= 1) { if (tid < s) red[tid] += red[tid + s]; __syncthreads(); }
    float mu = red[0] * (1.0f / D_MODEL);
    __syncthreads();
    float d = v - mu;
    red[tid] = d * d; __syncthreads();
    for (int s = 128; s > 0; s >>= 1) { if (tid < s) red[tid] += red[tid + s]; __syncthreads(); }
    float rstd = rsqrtf(red[0] * (1.0f / D_MODEL) + 1e-5f);
    y[row * D_MODEL + tid] = f2bf(d * rstd * g[tid] + b[tid]);
}

// ---------------- one-shot weight prep (all transposes + bias stack), flattened grid ----------------
__device__ __forceinline__ void wt_tile(const float* __restrict__ W, unsigned short* __restrict__ Wt,
                                        int K, int Nc, int n0, int k0, int tid,
                                        unsigned short (*tile)[33]) {
    int r = tid >> 3, cg = (tid & 7) * 4;
    float4 w4 = *(const float4*)&W[(size_t)(k0 + r) * Nc + n0 + cg];
    tile[r][cg + 0] = f2bf(w4.x); tile[r][cg + 1] = f2bf(w4.y);
    tile[r][cg + 2] = f2bf(w4.z); tile[r][cg + 3] = f2bf(w4.w);
    __syncthreads();
    int c = tid >> 3, rg = (tid & 7) * 4;
    u16x4 o;
    #pragma unroll
    for (int j = 0; j < 4; j++) o[j] = tile[rg + j][c];
    *(u16x4*)&Wt[(size_t)(n0 + c) * K + k0 + rg] = o;
}

__global__ void wt_all_kernel(const float* __restrict__ Wq, const float* __restrict__ Wk,
                              const float* __restrict__ Wv, const float* __restrict__ Wo,
                              const float* __restrict__ W1, const float* __restrict__ W2,
                              const float* __restrict__ W_emb, const float* __restrict__ W_out,
                              const float* __restrict__ bq, const float* __restrict__ bk,
                              const float* __restrict__ bv,
                              unsigned short* __restrict__ qkvt, unsigned short* __restrict__ wot,
                              unsigned short* __restrict__ w1t, unsigned short* __restrict__ w2t,
                              unsigned short* __restrict__ wembt, unsigned short* __restrict__ woutt,
                              float* __restrict__ bqkv) {
    __shared__ unsigned short tile[32][33];
    int b = blockIdx.x, tid = threadIdx.x;
    if (b < 512) {                       // qkv + o: 8 groups x 64 tiles
        int z = b >> 6, t = b & 63;
        int l = z >> 2, which = z & 3;
        const float* W = (which == 0 ? Wq : which == 1 ? Wk : which == 2 ? Wv : Wo) + (size_t)l * 65536;
        unsigned short* dst = (which < 3) ? qkvt + (size_t)l * 196608 + which * 65536
                                          : wot + (size_t)l * 65536;
        wt_tile(W, dst, 256, 256, (t & 7) * 32, (t >> 3) * 32, tid, tile);
    } else if (b < 1024) {               // ffn1: [L][256->1024]
        int b2 = b - 512, l = b2 >> 8, t = b2 & 255;
        wt_tile(W1 + (size_t)l * D_MODEL * D_FF, w1t + (size_t)l * D_MODEL * D_FF,
                D_MODEL, D_FF, (t & 31) * 32, (t >> 5) * 32, tid, tile);
    } else if (b < 1536) {               // ffn2: [L][1024->256]
        int b3 = b - 1024, l = b3 >> 8, t = b3 & 255;
        wt_tile(W2 + (size_t)l * D_FF * D_MODEL, w2t + (size_t)l * D_FF * D_MODEL,
                D_FF, D_MODEL, (t & 7) * 32, (t >> 3) * 32, tid, tile);
    } else if (b < 1568) {               // emb: K=128, Nc=256: 8x4 tiles
        int b4 = b - 1536;
        wt_tile(W_emb, wembt, D_FEAT, D_MODEL, (b4 & 7) * 32, (b4 >> 3) * 32, tid, tile);
    } else if (b < 1600) {               // out: K=256, Nc=128: 4x8 tiles
        int b5 = b - 1568;
        wt_tile(W_out, woutt, D_MODEL, D_OUT, (b5 & 3) * 32, (b5 >> 2) * 32, tid, tile);
    } else {                             // qkv bias stack: L*768 elements
        int i = (b - 1600) * 256 + tid;
        if (i < NLAYER * 768) {
            int l = i / 768, j = i % 768;
            const float* src = j < 256 ? bq : j < 512 ? bk : bv;
            bqkv[i] = src[l * 256 + (j & 255)];
        }
    }
}

// ---------------- bf16 MFMA GEMM, 32x64 tile, prefetched K-loop ----------------
template <int ACT, bool RESID, bool OUTBF16, bool AFP32>
__global__ void gemm_mfma_kernel(const void* __restrict__ Av,
                                 const unsigned short* __restrict__ Wt,
                                 const float* __restrict__ bias,
                                 float* __restrict__ C, unsigned short* __restrict__ Cb,
                                 int Nc, int K) {
    __shared__ __align__(16) unsigned short As[32][72];
    __shared__ __align__(16) unsigned short Bs[64][72];
    const unsigned short* A16 = (const unsigned short*)Av;
    const float* A32 = (const float*)Av;
    int tid = threadIdx.x;
    int m0 = blockIdx.y * 32, n0 = blockIdx.x * 64;
    int w = tid >> 6, lane = tid & 63;
    int rg = (w & 1) * 16, cg = (w >> 1) * 32;
    int m = lane & 15, quad = lane >> 4;
    f32x4 acc[2] = {{0.f, 0.f, 0.f, 0.f}, {0.f, 0.f, 0.f, 0.f}};
    int ar = tid >> 3, ac = (tid & 7) * 8;
    uint4 ra; float4 fa0, fa1; uint4 rb0, rb1;
    if (AFP32) {
        fa0 = *(const float4*)&A32[(size_t)(m0 + ar) * K + ac];
        fa1 = *(const float4*)&A32[(size_t)(m0 + ar) * K + ac + 4];
    } else {
        ra = *(const uint4*)&A16[(size_t)(m0 + ar) * K + ac];
    }
    rb0 = *(const uint4*)&Wt[(size_t)(n0 + ar) * K + ac];
    rb1 = *(const uint4*)&Wt[(size_t)(n0 + 32 + ar) * K + ac];
    for (int k0 = 0; k0 < K; k0 += 64) {
        if (AFP32) {
            u16x4 t0 = {f2bf(fa0.x), f2bf(fa0.y), f2bf(fa0.z), f2bf(fa0.w)};
            u16x4 t1 = {f2bf(fa1.x), f2bf(fa1.y), f2bf(fa1.z), f2bf(fa1.w)};
            *(u16x4*)&As[ar][ac] = t0;
            *(u16x4*)&As[ar][ac + 4] = t1;
        } else {
            *(uint4*)&As[ar][ac] = ra;
        }
        *(uint4*)&Bs[ar][ac] = rb0;
        *(uint4*)&Bs[ar + 32][ac] = rb1;
        __syncthreads();
        int kn = k0 + 64;
        if (kn < K) {   // prefetch next tile while MFMAs run
            if (AFP32) {
                fa0 = *(const float4*)&A32[(size_t)(m0 + ar) * K + kn + ac];
                fa1 = *(const float4*)&A32[(size_t)(m0 + ar) * K + kn + ac + 4];
            } else {
                ra = *(const uint4*)&A16[(size_t)(m0 + ar) * K + kn + ac];
            }
            rb0 = *(const uint4*)&Wt[(size_t)(n0 + ar) * K + kn + ac];
            rb1 = *(const uint4*)&Wt[(size_t)(n0 + 32 + ar) * K + kn + ac];
        }
        #pragma unroll
        for (int ks = 0; ks < 2; ks++) {
            short8 a = *(const short8*)&As[rg + m][ks * 32 + quad * 8];
            #pragma unroll
            for (int t = 0; t < 2; t++) {
                short8 b = *(const short8*)&Bs[cg + t * 16 + m][ks * 32 + quad * 8];
                acc[t] = __builtin_amdgcn_mfma_f32_16x16x32_bf16(a, b, acc[t], 0, 0, 0);
            }
        }
        __syncthreads();
    }
    #pragma unroll
    for (int t = 0; t < 2; t++) {
        #pragma unroll
        for (int reg = 0; reg < 4; reg++) {
            int row = m0 + rg + quad * 4 + reg;
            int col = n0 + cg + t * 16 + m;
            float val = acc[t][reg] + bias[col];
            if (ACT == 1) val = val * 0.5f * (1.0f + erff(val * 0.7071067811865476f));
            size_t idx = (size_t)row * Nc + col;
            if (RESID) val += C[idx];
            if (OUTBF16) Cb[idx] = f2bf(val);
            else C[idx] = val;
        }
    }
}

// ---------------- bf16 MFMA GEMM, 64x64 tile, prefetched; optional v^T side-write ----------------
template <int ACT, bool VBT>
__global__ void gemm64_kernel(const unsigned short* __restrict__ A,
                              const unsigned short* __restrict__ Wt,
                              const float* __restrict__ bias,
                              unsigned short* __restrict__ Cb,
                              unsigned short* __restrict__ vbt,
                              int Nc, int K) {
    __shared__ __align__(16) unsigned short As[64][72];
    __shared__ __align__(16) unsigned short Bs[64][72];
    int tid = threadIdx.x;
    int m0 = blockIdx.y * 64, n0 = blockIdx.x * 64;
    int w = tid >> 6, lane = tid & 63;
    int wr = (w & 1) * 32, wc = (w >> 1) * 32;
    int m = lane & 15, quad = lane >> 4;
    f32x4 acc[2][2] = {{{0.f,0.f,0.f,0.f},{0.f,0.f,0.f,0.f}},{{0.f,0.f,0.f,0.f},{0.f,0.f,0.f,0.f}}};
    int sr = tid >> 2, sg = (tid & 3) * 16;
    uint4 a0 = *(const uint4*)&A[(size_t)(m0 + sr) * K + sg];
    uint4 a1 = *(const uint4*)&A[(size_t)(m0 + sr) * K + sg + 8];
    uint4 b0 = *(const uint4*)&Wt[(size_t)(n0 + sr) * K + sg];
    uint4 b1 = *(const uint4*)&Wt[(size_t)(n0 + sr) * K + sg + 8];
    for (int k0 = 0; k0 < K; k0 += 64) {
        *(uint4*)&As[sr][sg] = a0;
        *(uint4*)&As[sr][sg + 8] = a1;
        *(uint4*)&Bs[sr][sg] = b0;
        *(uint4*)&Bs[sr][sg + 8] = b1;
        __syncthreads();
        int kn = k0 + 64;
        if (kn < K) {
            a0 = *(const uint4*)&A[(size_t)(m0 + sr) * K + kn + sg];
            a1 = *(const uint4*)&A[(size_t)(m0 + sr) * K + kn + sg + 8];
            b0 = *(const uint4*)&Wt[(size_t)(n0 + sr) * K + kn + sg];
            b1 = *(const uint4*)&Wt[(size_t)(n0 + sr) * K + kn + sg + 8];
        }
        #pragma unroll
        for (int kh = 0; kh < 2; kh++) {
            short8 x0 = *(const short8*)&As[wr + m][kh * 32 + quad * 8];
            short8 x1 = *(const short8*)&As[wr + 16 + m][kh * 32 + quad * 8];
            short8 y0 = *(const short8*)&Bs[wc + m][kh * 32 + quad * 8];
            short8 y1 = *(const short8*)&Bs[wc + 16 + m][kh * 32 + quad * 8];
            acc[0][0] = __builtin_amdgcn_mfma_f32_16x16x32_bf16(x0, y0, acc[0][0], 0, 0, 0);
            acc[0][1] = __builtin_amdgcn_mfma_f32_16x16x32_bf16(x0, y1, acc[0][1], 0, 0, 0);
            acc[1][0] = __builtin_amdgcn_mfma_f32_16x16x32_bf16(x1, y0, acc[1][0], 0, 0, 0);
            acc[1][1] = __builtin_amdgcn_mfma_f32_16x16x32_bf16(x1, y1, acc[1][1], 0, 0, 0);
        }
        __syncthreads();
    }
    #pragma unroll
    for (int mt = 0; mt < 2; mt++) {
        #pragma unroll
        for (int nt = 0; nt < 2; nt++) {
            #pragma unroll
            for (int reg = 0; reg < 4; reg++) {
                int row = m0 + wr + mt * 16 + quad * 4 + reg;
                int col = n0 + wc + nt * 16 + m;
                float val = acc[mt][nt][reg] + bias[col];
                if (ACT == 1) val = val * 0.5f * (1.0f + erff(val * 0.7071067811865476f));
                unsigned short bv = f2bf(val);
                Cb[(size_t)row * Nc + col] = bv;
                if (VBT && col >= 512)
                    vbt[(size_t)(col - 512) * N_NODES + row] = bv;
            }
        }
    }
}

// ---------------- flash attention v3: register spd LUT, DPP softmax, float-P reuse ----------------
// grid (N/64, H, JSPLIT), block 256 = 4 waves; wave w owns rows w*16..+16.
__global__ __launch_bounds__(256)
void flash_attn_kernel(const unsigned short* __restrict__ qkvb,
                       const unsigned short* __restrict__ vbt,
                       const unsigned char* __restrict__ bucket,
                       const float* __restrict__ spd_l,
                       const float* __restrict__ et_l,
                       const unsigned* __restrict__ offsets,
                       const unsigned* __restrict__ packed,
                       float* __restrict__ part_O,
                       float* __restrict__ m_part, float* __restrict__ l_part) {
    __shared__ __align__(16) unsigned short ks[64][40];
    __shared__ __align__(16) unsigned short vs[32][72];
    __shared__ __align__(16) float ov[64][68];   // spd+edge bias tile; reused as float-P (own wave rows)
    __shared__ float et[8];

    int tid = threadIdx.x;
    int rb = blockIdx.x;
    int i0 = rb * 64;
    int hh = blockIdx.y;
    int js = blockIdx.z;
    int lane = tid & 63;
    if (tid < 8) et[tid] = et_l[tid * NHEAD + hh];
    float spd_reg = spd_l[(lane < 11 ? lane : 10) * NHEAD + hh];   // lane i holds spd[i]

    int w = tid >> 6;
    int m = lane & 15, quad = lane >> 4;
    int r0 = w * 16;
    short8 aq = *(const short8*)&qkvb[(size_t)(i0 + r0 + m) * 768 + hh * DH + quad * 8];
    float m_st[4], l_st[4];
    #pragma unroll
    for (int r = 0; r < 4; r++) { m_st[r] = -3.0e38f; l_st[r] = 0.f; }
    f32x4 oacc[2] = {{0.f, 0.f, 0.f, 0.f}, {0.f, 0.f, 0.f, 0.f}};
    const float scale = 0.17677669529663687f;

    int krow = tid >> 2, kcol = (tid & 3) * 8;
    int vrow = tid >> 3, vcol = (tid & 7) * 8;
    int brow = tid >> 2, bcol = (tid & 3) * 16;

    for (int jt = 0; jt < N_NODES / JSPLIT / 64; jt++) {
        int j0 = js * (N_NODES / JSPLIT) + jt * 64;
        __syncthreads();   // previous iteration fully consumed
        *(uint4*)&ks[krow][kcol] =
            *(const uint4*)&qkvb[(size_t)(j0 + krow) * 768 + 256 + hh * DH + kcol];
        *(uint4*)&vs[vrow][vcol] =
            *(const uint4*)&vbt[(size_t)(hh * DH + vrow) * N_NODES + j0 + vcol];
        {   // bias tile: spd gather via ds_bpermute on the register LUT, vectorized store
            uint4 b16 = *(const uint4*)&bucket[(size_t)(i0 + brow) * N_NODES + j0 + bcol];
            const unsigned char* bb = (const unsigned char*)&b16;
            float fb[16];
            #pragma unroll
            for (int i = 0; i < 16; i++)
                fb[i] = __int_as_float(
                    __builtin_amdgcn_ds_bpermute(((int)bb[i]) << 2, __float_as_int(spd_reg)));
            #pragma unroll
            for (int g = 0; g < 4; g++) {
                f32x4 st = {fb[g * 4], fb[g * 4 + 1], fb[g * 4 + 2], fb[g * 4 + 3]};
                *(f32x4*)&ov[brow][bcol + g * 4] = st;
            }
        }
        __syncthreads();   // bias tile initialized
        {   // sparse edge bias
            unsigned key0 = (unsigned)rb * 2048 + j0;
            unsigned start = offsets[key0], end = offsets[key0 + 64];
            for (unsigned i = start + tid; i < end; i += 256) {
                unsigned p = packed[i];
                atomicAdd(&ov[(p >> 11) & 63][(p & 2047) - j0], et[(p >> 17) & 7]);
            }
        }
        __syncthreads();   // edges applied
        // S = QK^T*scale + bias (C-layout registers)
        float sv[4][4];
        #pragma unroll
        for (int t = 0; t < 4; t++) {
            short8 bk8 = *(const short8*)&ks[t * 16 + m][quad * 8];
            f32x4 z = {0.f, 0.f, 0.f, 0.f};
            f32x4 sacc = __builtin_amdgcn_mfma_f32_16x16x32_bf16(aq, bk8, z, 0, 0, 0);
            #pragma unroll
            for (int r = 0; r < 4; r++)
                sv[t][r] = sacc[r] * scale + ov[r0 + quad * 4 + r][t * 16 + m];
        }
        // online softmax: 16-lane row reductions via DPP rotates (VALU pipe)
        float alpha[4];
        #pragma unroll
        for (int r = 0; r < 4; r++) {
            float mx = fmaxf(fmaxf(sv[0][r], sv[1][r]), fmaxf(sv[2][r], sv[3][r]));
            mx = fmaxf(mx, dpp_ror<0x121>(mx));
            mx = fmaxf(mx, dpp_ror<0x122>(mx));
            mx = fmaxf(mx, dpp_ror<0x124>(mx));
            mx = fmaxf(mx, dpp_ror<0x128>(mx));
            float mn = fmaxf(m_st[r], mx);
            alpha[r] = __expf(m_st[r] - mn);
            m_st[r] = mn;
            float ps = 0.f;
            #pragma unroll
            for (int t = 0; t < 4; t++) { float pv = __expf(sv[t][r] - mn); sv[t][r] = pv; ps += pv; }
            ps += dpp_ror<0x121>(ps);
            ps += dpp_ror<0x122>(ps);
            ps += dpp_ror<0x124>(ps);
            ps += dpp_ror<0x128>(ps);
            l_st[r] = l_st[r] * alpha[r] + ps;
        }
        // float P into own wave's rows of ov (C-layout write, 2-way banks)
        #pragma unroll
        for (int t = 0; t < 4; t++)
            #pragma unroll
            for (int r = 0; r < 4; r++)
                ov[r0 + quad * 4 + r][t * 16 + m] = sv[t][r];
        #pragma unroll
        for (int r = 0; r < 4; r++) { oacc[0][r] *= alpha[r]; oacc[1][r] *= alpha[r]; }
        __builtin_amdgcn_s_waitcnt(0xC07F);   // lgkmcnt(0): own P writes visible
        #pragma unroll
        for (int kh = 0; kh < 2; kh++) {
            f32x4 p0 = *(const f32x4*)&ov[r0 + m][kh * 32 + quad * 8];
            f32x4 p1 = *(const f32x4*)&ov[r0 + m][kh * 32 + quad * 8 + 4];
            short8 pa;
            pa[0] = (short)f2bf(p0[0]); pa[1] = (short)f2bf(p0[1]);
            pa[2] = (short)f2bf(p0[2]); pa[3] = (short)f2bf(p0[3]);
            pa[4] = (short)f2bf(p1[0]); pa[5] = (short)f2bf(p1[1]);
            pa[6] = (short)f2bf(p1[2]); pa[7] = (short)f2bf(p1[3]);
            #pragma unroll
            for (int t = 0; t < 2; t++) {
                short8 vb = *(const short8*)&vs[t * 16 + m][kh * 32 + quad * 8];
                oacc[t] = __builtin_amdgcn_mfma_f32_16x16x32_bf16(pa, vb, oacc[t], 0, 0, 0);
            }
        }
    }
    #pragma unroll
    for (int t = 0; t < 2; t++)
        #pragma unroll
        for (int r = 0; r < 4; r++)
            part_O[((size_t)js * N_NODES + i0 + r0 + quad * 4 + r) * D_MODEL + hh * DH + t * 16 + m] =
                oacc[t][r];
    if (m == 0) {
        #pragma unroll
        for (int r = 0; r < 4; r++) {
            int row = i0 + r0 + quad * 4 + r;
            m_part[((size_t)js * NHEAD + hh) * N_NODES + row] = m_st[r];
            l_part[((size_t)js * NHEAD + hh) * N_NODES + row] = l_st[r];
        }
    }
}

// ---------------- merge j-split partials -> bf16 attn out ----------------
__global__ void flash_merge_kernel(const float* __restrict__ part_O,
                                   const float* __restrict__ m_part,
                                   const float* __restrict__ l_part,
                                   unsigned short* __restrict__ aoutb) {
    int e = blockIdx.x * 256 + threadIdx.x;
    int row = e >> 8, col = e & 255, h = col >> 5;
    float mv[JSPLIT];
    float mg = -3.0e38f;
    #pragma unroll
    for (int js = 0; js < JSPLIT; js++) {
        mv[js] = m_part[((size_t)js * NHEAD + h) * N_NODES + row];
        mg = fmaxf(mg, mv[js]);
    }
    float o = 0.f, l = 0.f;
    #pragma unroll
    for (int js = 0; js < JSPLIT; js++) {
        float sc = __expf(mv[js] - mg);
        o += sc * part_O[(size_t)js * N_NODES * D_MODEL + e];
        l += sc * l_part[((size_t)js * NHEAD + h) * N_NODES + row];
    }
    aoutb[e] = f2bf(o / l);
}

extern "C" void kernel_launch(void* const* d_in, const int* in_sizes, int n_in,
                              void* d_out, int out_size, void* d_ws, size_t ws_size,
                              hipStream_t stream) {
    const float* x          = (const float*)d_in[0];
    const int*   edge_index = (const int*)d_in[1];
    const int*   edge_types = (const int*)d_in[2];
    const float* pos        = (const float*)d_in[3];
    const float* W_emb      = (const float*)d_in[4];
    const float* b_emb      = (const float*)d_in[5];
    const float* Wq         = (const float*)d_in[6];
    const float* Wk         = (const float*)d_in[7];
    const float* Wv         = (const float*)d_in[8];
    const float* Wo         = (const float*)d_in[9];
    const float* bq         = (const float*)d_in[10];
    const float* bk         = (const float*)d_in[11];
    const float* bv         = (const float*)d_in[12];
    const float* bo         = (const float*)d_in[13];
    const float* spd_table  = (const float*)d_in[14];
    const float* edge_table = (const float*)d_in[15];
    const float* din_emb    = (const float*)d_in[16];
    const float* dout_emb   = (const float*)d_in[17];
    const float* ln1_g      = (const float*)d_in[18];
    const float* ln1_b      = (const float*)d_in[19];
    const float* ln2_g      = (const float*)d_in[20];
    const float* ln2_b      = (const float*)d_in[21];
    const float* W1         = (const float*)d_in[22];
    const float* b1         = (const float*)d_in[23];
    const float* W2         = (const float*)d_in[24];
    const float* b2         = (const float*)d_in[25];
    const float* W_out      = (const float*)d_in[26];
    const float* b_out      = (const float*)d_in[27];
    float* out = (float*)d_out;

    char* base = (char*)d_ws;
    int* deg_out = (int*)base;                    base += (size_t)N_NODES * 4;
    int* deg_in  = (int*)base;                    base += (size_t)N_NODES * 4;
    float* h     = (float*)base;                  base += (size_t)N_NODES * D_MODEL * 4;
    unsigned short* xb   = (unsigned short*)base; base += (size_t)N_NODES * D_MODEL * 2;
    unsigned short* qkvb = (unsigned short*)base; base += (size_t)N_NODES * 768 * 2;
    unsigned short* vbt  = (unsigned short*)base; base += (size_t)D_MODEL * N_NODES * 2;
    unsigned short* aoutb = (unsigned short*)base; base += (size_t)N_NODES * D_MODEL * 2;
    unsigned short* ffnb = (unsigned short*)base; base += (size_t)N_NODES * D_FF * 2;
    unsigned char* bucket = (unsigned char*)base; base += (size_t)N_NODES * N_NODES;
    unsigned short* qkvt = (unsigned short*)base; base += (size_t)NLAYER * 768 * D_MODEL * 2;
    unsigned short* wot  = (unsigned short*)base; base += (size_t)NLAYER * D_MODEL * D_MODEL * 2;
    unsigned short* w1t  = (unsigned short*)base; base += (size_t)NLAYER * D_MODEL * D_FF * 2;
    unsigned short* w2t  = (unsigned short*)base; base += (size_t)NLAYER * D_FF * D_MODEL * 2;
    unsigned short* wembt = (unsigned short*)base; base += (size_t)D_FEAT * D_MODEL * 2;
    unsigned short* woutt = (unsigned short*)base; base += (size_t)D_MODEL * D_OUT * 2;
    float* bqkv = (float*)base;                   base += (size_t)NLAYER * 768 * 4;
    unsigned* hist    = (unsigned*)base;          base += (size_t)65536 * 4;
    unsigned* offsets = (unsigned*)base;          base += (size_t)65537 * 4;
    unsigned* cursor  = (unsigned*)base;          base += (size_t)65536 * 4;
    unsigned* blocksum = (unsigned*)base;         base += (size_t)256 * 4;
    unsigned* packed  = (unsigned*)base;          base += (size_t)NEDGE * 4;
    float* part_O = (float*)base;                 base += (size_t)JSPLIT * N_NODES * D_MODEL * 4;
    float* m_part = (float*)base;                 base += (size_t)JSPLIT * NHEAD * N_NODES * 4;
    float* l_part = (float*)base;                 base += (size_t)JSPLIT * NHEAD * N_NODES * 4;

    hipMemsetAsync(deg_out, 0, (size_t)N_NODES * 4 * 2, stream);
    hipMemsetAsync(hist, 0, (size_t)65536 * 4, stream);

    degree_hist_kernel<<<NEDGE / 256, 256, 0, stream>>>(edge_index, deg_out, deg_in, hist);
    edge_scan1_kernel<<<256, 256, 0, stream>>>(hist, offsets, blocksum);
    edge_scan2_kernel<<<1, 256, 0, stream>>>(blocksum);
    edge_scan3_kernel<<<256, 256, 0, stream>>>(blocksum, offsets, cursor);
    edge_scatter_kernel<<<NEDGE / 256, 256, 0, stream>>>(edge_index, edge_types, cursor, packed);
    wt_all_kernel<<<1606, 256, 0, stream>>>(Wq, Wk, Wv, Wo, W1, W2, W_emb, W_out,
                                            bq, bk, bv, qkvt, wot, w1t, w2t, wembt, woutt, bqkv);
    bucket_kernel<<<(size_t)N_NODES * N_NODES / 4 / 256, 256, 0, stream>>>(pos, bucket);

    // embed: h = x @ W_emb + b_emb (fp32 A, cast in staging)
    gemm_mfma_kernel<0, false, false, true><<<dim3(D_MODEL / 64, N_NODES / 32), 256, 0, stream>>>(
        x, wembt, b_emb, h, nullptr, D_MODEL, D_FEAT);

    for (int l = 0; l < NLAYER; l++) {
        centrality_ln_kernel<<<N_NODES, 256, 0, stream>>>(
            h, din_emb + (size_t)l * (MAXDEG + 1) * D_MODEL,
            dout_emb + (size_t)l * (MAXDEG + 1) * D_MODEL, deg_in, deg_out,
            ln1_g + l * D_MODEL, ln1_b + l * D_MODEL, xb);

        gemm64_kernel<0, true><<<dim3(768 / 64, N_NODES / 64), 256, 0, stream>>>(
            xb, qkvt + (size_t)l * 768 * D_MODEL, bqkv + l * 768, qkvb, vbt, 768, D_MODEL);

        flash_attn_kernel<<<dim3(N_NODES / 64, NHEAD, JSPLIT), 256, 0, stream>>>(
            qkvb, vbt, bucket, spd_table + (size_t)l * 11 * NHEAD,
            edge_table + (size_t)l * 8 * NHEAD, offsets, packed, part_O, m_part, l_part);

        flash_merge_kernel<<<N_NODES * D_MODEL / 256, 256, 0, stream>>>(part_O, m_part, l_part, aoutb);

        gemm_mfma_kernel<0, true, false, false><<<dim3(D_MODEL / 64, N_NODES / 32), 256, 0, stream>>>(
            aoutb, wot + (size_t)l * D_MODEL * D_MODEL, bo + l * D_MODEL, h, nullptr, D_MODEL, D_MODEL);

        layernorm_kernel<<<N_NODES, 256, 0, stream>>>(h, ln2_g + l * D_MODEL, ln2_b + l * D_MODEL, xb);

        gemm64_kernel<1, false><<<dim3(D_FF / 64, N_NODES / 64), 256, 0, stream>>>(
            xb, w1t + (size_t)l * D_MODEL * D_FF, b1 + l * D_FF, ffnb, nullptr, D_FF, D_MODEL);

        gemm_mfma_kernel<0, true, false, false><<<dim3(D_MODEL / 64, N_NODES / 32), 256, 0, stream>>>(
            ffnb, w2t + (size_t)l * D_FF * D_MODEL, b2 + l * D_MODEL, h, nullptr, D_MODEL, D_FF);
    }

    // final: out = h @ W_out + b_out (fp32 A, cast in staging)
    gemm_mfma_kernel<0, false, false, true><<<dim3(D_OUT / 64, N_NODES / 32), 256, 0, stream>>>(
        h, woutt, b_out, out, nullptr, D_OUT, D_MODEL);
}